// Round 8
// baseline (570.413 us; speedup 1.0000x reference)
//
#include <hip/hip_runtime.h>

// ---------------------------------------------------------------------------
// lm_ot: LM softmax distributions + Sinkhorn OT, fused pipeline for MI355X.
// Sizes fixed by setup_inputs(): B=512, H=1024, V=28996, NV=3000, SLOTS=33.
// R13: R12 + __launch_bounds__(1024, 4). R12's counters showed the compiler
//   capped VGPR at 64 (default heuristic: 8 waves/SIMD) and spilled kr[] to
//   scratch: WRITE 48KB->98MB, FETCH 5.4MB->416MB (kr re-read from scratch
//   every kpass), VALUBusy 25%, 335us. (1024,4) = 4 waves/SIMD = 16 waves/CU
//   = the 1 block/CU we already run at, raising the VGPR cap to 128 so the
//   R11 design (1-barrier iter + redundant ured + 3 K rows pinned) is finally
//   measured without the spill confound.
// ---------------------------------------------------------------------------
#define NV 3000
#define HH 1024
#define BB 512

typedef __attribute__((ext_vector_type(8))) short short8;
typedef __attribute__((ext_vector_type(4))) float floatx4;

__device__ __forceinline__ float wave_sum(float x) {
#pragma unroll
  for (int off = 32; off; off >>= 1) x += __shfl_xor(x, off, 64);
  return x;
}
__device__ __forceinline__ unsigned bf16r(float x) {  // fp32 -> bf16 bits, RNE
  unsigned u = __float_as_uint(x);
  u += 0x7fffu + ((u >> 16) & 1u);
  return u >> 16;
}
__device__ __forceinline__ void gload16(const void* g, void* l) {
  // async global->LDS DMA; HW dst = wave-uniform base + lane*16B.
  __builtin_amdgcn_global_load_lds(
      (const __attribute__((address_space(1))) unsigned*)g,
      (__attribute__((address_space(3))) unsigned*)l, 16, 0, 0);
}

// packed 2xf32 fma: acc = a*b + acc (single VOP3P instruction)
__device__ __forceinline__ void pk_fma_acc(float2& acc, float2 a, float2 b) {
  asm("v_pk_fma_f32 %0, %1, %2, %0" : "+v"(acc) : "v"(a), "v"(b));
}
// unpack a packed-bf16 dword (lo = slot 2j, hi = slot 2j+1) to float2
__device__ __forceinline__ float2 unpk2(unsigned d) {
  float2 r;
  r.x = __uint_as_float(d << 16);
  r.y = __uint_as_float(d & 0xffff0000u);
  return r;
}

// --- norms of gathered W rows + topics, AND bf16 gather Wb[3072][1024] ------
__global__ __launch_bounds__(256) void norms_wb_kernel(
    const float* __restrict__ W_lm, const float* __restrict__ topics,
    const int* __restrict__ verbs, float* __restrict__ vninv,
    float* __restrict__ tninv, unsigned short* __restrict__ Wb) {
  int r = blockIdx.x, t = threadIdx.x;
  bool isW = r < 3072;
  int j = isW ? (r < NV ? r : NV - 1) : 0;
  const float* src = isW ? (W_lm + (size_t)verbs[j] * HH)
                         : (topics + (size_t)(r - 3072) * HH);
  float4 v = *(const float4*)(src + t * 4);
  if (isW) {
    *(uint2*)(Wb + (size_t)r * HH + t * 4) =
        make_uint2(bf16r(v.x) | (bf16r(v.y) << 16),
                   bf16r(v.z) | (bf16r(v.w) << 16));
  }
  float ss = v.x * v.x + v.y * v.y + v.z * v.z + v.w * v.w;
  ss = wave_sum(ss);
  __shared__ float sq[4];
  if ((t & 63) == 0) sq[t >> 6] = ss;
  __syncthreads();
  if (t == 0) {
    float inv = 1.0f / (sqrtf(sq[0] + sq[1] + sq[2] + sq[3]) + 1e-8f);
    if (isW) { if (r < NV) vninv[r] = inv; }
    else tninv[r - 3072] = inv;
  }
}

// --- Xb[1024][1024] bf16: rows 0..511 = inputs[:, :1024], 512.. = [:,1024:] -
__global__ __launch_bounds__(256) void xb_kernel(
    const float* __restrict__ inputs, unsigned short* __restrict__ Xb) {
  int idx = blockIdx.x * 256 + threadIdx.x;  // < 131072
  int r = idx >> 7, c8 = (idx & 127) << 3;
  const float* src = (r < 512) ? (inputs + (size_t)r * 2048 + c8)
                               : (inputs + (size_t)(r - 512) * 2048 + 1024 + c8);
  float4 x0 = ((const float4*)src)[0];
  float4 x1 = ((const float4*)src)[1];
  uint4 o;
  o.x = bf16r(x0.x) | (bf16r(x0.y) << 16);
  o.y = bf16r(x0.z) | (bf16r(x0.w) << 16);
  o.z = bf16r(x1.x) | (bf16r(x1.y) << 16);
  o.w = bf16r(x1.z) | (bf16r(x1.w) << 16);
  *(uint4*)(Xb + (size_t)r * HH + c8) = o;
}

// --- topT[k][s] = topics[s][k] * tninv[s]  (transposed+scaled, 1024x32) -----
__global__ __launch_bounds__(256) void topt_kernel(
    const float* __restrict__ topics, const float* __restrict__ tninv,
    float* __restrict__ topT) {
  int idx = blockIdx.x * 256 + threadIdx.x;  // = k*32 + s, < 32768
  int k = idx >> 5, s = idx & 31;
  topT[idx] = topics[(size_t)s * HH + k] * tninv[s];
}

// --- aT[row][0..31] = softmax((outputs @ W_lin^T + b_lin)[row, 1:33]) -------
__global__ __launch_bounds__(64) void a_kernel(
    const float* __restrict__ outputs, const float* __restrict__ W_lin,
    const float* __restrict__ b_lin, float* __restrict__ aT) {
  int r = blockIdx.x, t = threadIdx.x;
  __shared__ float orow[512];
  __shared__ float lg[33];
  __shared__ float ms[2];
  *(float4*)(orow + t * 8)     = *(const float4*)(outputs + (size_t)r * 512 + t * 8);
  *(float4*)(orow + t * 8 + 4) = *(const float4*)(outputs + (size_t)r * 512 + t * 8 + 4);
  __syncthreads();
  if (t < 33) {
    float acc = b_lin[t];
    for (int k = 0; k < 512; ++k) acc = fmaf(orow[k], W_lin[(size_t)t * 512 + k], acc);
    lg[t] = acc;
  }
  __syncthreads();
  if (t == 0) {
    float m = lg[1];
    for (int i = 2; i < 33; ++i) m = fmaxf(m, lg[i]);
    float ssum = 0.0f;
    for (int i = 1; i < 33; ++i) ssum += __expf(lg[i] - m);
    ms[0] = m; ms[1] = ssum;
  }
  __syncthreads();
  if (t >= 1 && t < 33) aT[(size_t)r * 32 + t - 1] = __expf(lg[t] - ms[0]) / ms[1];
}

// --- MFMA logits GEMM: L[1024][3000] = 0.5 * Xb @ Wb^T  (bf16 in, f32 out) --
__global__ __launch_bounds__(256) void gemm_mfma(
    const unsigned short* __restrict__ Xb, const unsigned short* __restrict__ Wb,
    float* __restrict__ L) {
  __shared__ unsigned short As[128 * 32], Bs[128 * 32];
  int t = threadIdx.x;
  int wave = t >> 6, ln = t & 63;
  int bn = blockIdx.x, bm = blockIdx.y;
  int wm = (wave >> 1) * 64, wn = (wave & 1) * 64;
  const unsigned short* ga = Xb + (size_t)(bm * 128 + (t >> 2)) * HH + (t & 3) * 8;
  const unsigned short* gb = Wb + (size_t)(bn * 128 + (t >> 2)) * HH + (t & 3) * 8;
  int lq = ln >> 4, lm = ln & 15;
  floatx4 acc[4][4];
#pragma unroll
  for (int i = 0; i < 4; ++i)
#pragma unroll
    for (int j = 0; j < 4; ++j) acc[i][j] = (floatx4)0.0f;

  for (int k0 = 0; k0 < HH; k0 += 32) {
    __syncthreads();
    gload16(ga + k0, As + t * 8);
    gload16(ga + (size_t)64 * HH + k0, As + 2048 + t * 8);
    gload16(gb + k0, Bs + t * 8);
    gload16(gb + (size_t)64 * HH + k0, Bs + 2048 + t * 8);
    __syncthreads();
    short8 af[4], bfr[4];
#pragma unroll
    for (int i = 0; i < 4; ++i)
      af[i] = *(const short8*)(As + (wm + i * 16 + lm) * 32 + lq * 8);
#pragma unroll
    for (int j = 0; j < 4; ++j)
      bfr[j] = *(const short8*)(Bs + (wn + j * 16 + lm) * 32 + lq * 8);
#pragma unroll
    for (int i = 0; i < 4; ++i)
#pragma unroll
      for (int j = 0; j < 4; ++j)
        acc[i][j] = __builtin_amdgcn_mfma_f32_16x16x32_bf16(af[i], bfr[j], acc[i][j], 0, 0, 0);
  }
  int row0 = bm * 128 + wm + lq * 4;
  int col0 = bn * 128 + wn + lm;
#pragma unroll
  for (int j = 0; j < 4; ++j) {
    int col = col0 + j * 16;
    if (col < NV) {
#pragma unroll
      for (int i = 0; i < 4; ++i) {
#pragma unroll
        for (int r = 0; r < 4; ++r)
          L[(size_t)(row0 + i * 16 + r) * NV + col] = acc[i][j][r] * 0.5f;
      }
    }
  }
}

// --- per-row: bT = renorm(0.5*(softmax(L1)+softmax(L2))), in-place over L1 ---
__global__ __launch_bounds__(256) void softmax_kernel(
    float* __restrict__ L1, const float* __restrict__ L2) {
  int r = blockIdx.x, t = threadIdx.x, w = t >> 6, ln = t & 63;
  float* row1 = L1 + (size_t)r * NV;
  const float* row2 = L2 + (size_t)r * NV;
  __shared__ float rd[2][4];
  float s1 = 0.0f, s2 = 0.0f;
  for (int v = t; v < NV; v += 256) { s1 += __expf(row1[v]); s2 += __expf(row2[v]); }
  s1 = wave_sum(s1); s2 = wave_sum(s2);
  if (ln == 0) { rd[0][w] = s1; rd[1][w] = s2; }
  __syncthreads();
  s1 = rd[0][0] + rd[0][1] + rd[0][2] + rd[0][3];
  s2 = rd[1][0] + rd[1][1] + rd[1][2] + rd[1][3];
  float i1 = 0.5f / s1, i2 = 0.5f / s2;
  float rs = 0.0f;
  for (int v = t; v < NV; v += 256) {
    float o = __expf(row1[v]) * i1 + __expf(row2[v]) * i2;
    row1[v] = o; rs += o;
  }
  rs = wave_sum(rs);
  __syncthreads();
  if (ln == 0) rd[0][w] = rs;
  __syncthreads();
  float rinv = 1.0f / (rd[0][0] + rd[0][1] + rd[0][2] + rd[0][3]);
  for (int v = t; v < NV; v += 256) row1[v] *= rinv;
}

// --- Kb[v][s]=bf16(exp(-20*M)) packed, KMt[v][s]=K*M fp32 ------------------
__global__ __launch_bounds__(256) void mk_kernel(
    const float* __restrict__ W_lm, const int* __restrict__ verbs,
    const float* __restrict__ topT, const float* __restrict__ vninv,
    unsigned* __restrict__ Kb, float* __restrict__ KMt) {
  __shared__ float red[4][64][33];
  int t = threadIdx.x, ln = t & 63, w = t >> 6;
  int v = blockIdx.x * 64 + ln;
  int vc = v < NV ? v : NV - 1;
  int kb = __builtin_amdgcn_readfirstlane(w) << 8;
  const float* wrow = W_lm + (size_t)verbs[vc] * HH + kb;
  const float* tb = topT + (size_t)kb * 32;
  float acc[32];
#pragma unroll
  for (int s = 0; s < 32; ++s) acc[s] = 0.0f;
  for (int kk = 0; kk < 256; kk += 4) {
    float4 w4 = *(const float4*)(wrow + kk);
    const float* tr = tb + kk * 32;
    const float* pw = (const float*)&w4;
#pragma unroll
    for (int d = 0; d < 4; ++d)
#pragma unroll
      for (int s = 0; s < 32; ++s) acc[s] = fmaf(pw[d], tr[d * 32 + s], acc[s]);
  }
#pragma unroll
  for (int s = 0; s < 32; ++s) red[w][ln][s] = acc[s];
  __syncthreads();
  for (int idx = t; idx < 1024; idx += 256) {
    int l = idx >> 4, pr = idx & 15;
    int vo = blockIdx.x * 64 + l;
    if (vo < NV) {
      int s0 = pr * 2, s1 = s0 + 1;
      float vi = vninv[vo];
      float d0 = red[0][l][s0] + red[1][l][s0] + red[2][l][s0] + red[3][l][s0];
      float d1 = red[0][l][s1] + red[1][l][s1] + red[2][l][s1] + red[3][l][s1];
      float M0 = 1.0f - d0 * vi, M1 = 1.0f - d1 * vi;
      float K0 = __expf(-20.0f * M0), K1 = __expf(-20.0f * M1);
      *(float2*)(KMt + (size_t)vo * 32 + s0) = make_float2(K0 * M0, K1 * M1);
      Kb[(size_t)vo * 16 + pr] = bf16r(K0) | (bf16r(K1) << 16);
    }
  }
}

// --- manual grid barrier: monotone counter, agent-scope atomics -------------
__device__ __forceinline__ void gridbar(unsigned* bar, unsigned target) {
  __syncthreads();
  if (threadIdx.x == 0) {
    __hip_atomic_fetch_add(bar, 1u, __ATOMIC_RELEASE, __HIP_MEMORY_SCOPE_AGENT);
    while (__hip_atomic_load(bar, __ATOMIC_ACQUIRE, __HIP_MEMORY_SCOPE_AGENT) < target) {
      __builtin_amdgcn_s_sleep(1);
    }
  }
  __syncthreads();
}

// slot-split fused pass: pair (2k,2k+1) shares each v-row; lane parity p owns
// slots [16p,16p+16). Full w rebuilt via shfl_xor(.,1). 512 pairs x 6 rows.
// Rows i<3 come from registers kr[] (K is iteration-invariant); i>=3 from L2.
template <bool STORE_T>
__device__ __forceinline__ void kpass_ss(
    const uint4* __restrict__ Kb, const uint4* kr,
    const float* __restrict__ bsh0, const float* __restrict__ bsh1,
    const float2* u0, const float2* u1, float2* z0, float2* z1,
    float* vsh0, float* vsh1, int pid, int p) {
#pragma unroll
  for (int i = 0; i < 6; ++i) {
    int v = pid + (i << 9);
    if (i < 5 || v < NV) {
      uint4 q0, q1;
      if (i < 3) {
        q0 = kr[2 * i]; q1 = kr[2 * i + 1];
      } else {
        const uint4* kq = Kb + ((size_t)v << 2) + (p << 1);
        q0 = kq[0]; q1 = kq[1];
      }
      float2 kc[8];
      kc[0] = unpk2(q0.x); kc[1] = unpk2(q0.y);
      kc[2] = unpk2(q0.z); kc[3] = unpk2(q0.w);
      kc[4] = unpk2(q1.x); kc[5] = unpk2(q1.y);
      kc[6] = unpk2(q1.z); kc[7] = unpk2(q1.w);
      float2 w0 = make_float2(0.f, 0.f), w1 = make_float2(0.f, 0.f);
#pragma unroll
      for (int j = 0; j < 8; ++j) { pk_fma_acc(w0, kc[j], u0[j]); pk_fma_acc(w1, kc[j], u1[j]); }
      float s0 = w0.x + w0.y, s1 = w1.x + w1.y;
      s0 += __shfl_xor(s0, 1, 64);
      s1 += __shfl_xor(s1, 1, 64);
      float t0 = bsh0[v] * __builtin_amdgcn_rcpf(s0);
      float t1 = bsh1[v] * __builtin_amdgcn_rcpf(s1);
      if (STORE_T && !p) { vsh0[v] = t0; vsh1[v] = t1; }
      float2 t0p = make_float2(t0, t0), t1p = make_float2(t1, t1);
#pragma unroll
      for (int j = 0; j < 8; ++j) { pk_fma_acc(z0[j], kc[j], t0p); pk_fma_acc(z1[j], kc[j], t1p); }
    }
  }
}

__device__ __forceinline__ void errpass_ss(
    const uint4* __restrict__ Kb, const uint4* kr,
    const float* __restrict__ bsh0, const float* __restrict__ bsh1,
    const float2* u0, const float2* u1,
    const float* vsh0, const float* vsh1, float& ep0, float& ep1,
    int pid, int p) {
#pragma unroll
  for (int i = 0; i < 6; ++i) {
    int v = pid + (i << 9);
    if (i < 5 || v < NV) {
      uint4 q0, q1;
      if (i < 3) {
        q0 = kr[2 * i]; q1 = kr[2 * i + 1];
      } else {
        const uint4* kq = Kb + ((size_t)v << 2) + (p << 1);
        q0 = kq[0]; q1 = kq[1];
      }
      float2 kc[8];
      kc[0] = unpk2(q0.x); kc[1] = unpk2(q0.y);
      kc[2] = unpk2(q0.z); kc[3] = unpk2(q0.w);
      kc[4] = unpk2(q1.x); kc[5] = unpk2(q1.y);
      kc[6] = unpk2(q1.z); kc[7] = unpk2(q1.w);
      float2 w0 = make_float2(0.f, 0.f), w1 = make_float2(0.f, 0.f);
#pragma unroll
      for (int j = 0; j < 8; ++j) { pk_fma_acc(w0, kc[j], u0[j]); pk_fma_acc(w1, kc[j], u1[j]); }
      float s0 = w0.x + w0.y, s1 = w1.x + w1.y;
      s0 += __shfl_xor(s0, 1, 64);
      s1 += __shfl_xor(s1, 1, 64);
      if (!p) {
        ep0 += fabsf(vsh0[v] * s0 - bsh0[v]);
        ep1 += fabsf(vsh1[v] * s1 - bsh1[v]);
      }
    }
  }
}

// 16-element reduce-scatter butterfly over strides 2..32 (parity classes stay
// separate). Lane ln ends holding the total of slot
// s = (ln&1)*16 + brev4((ln>>1)&15).
__device__ __forceinline__ float waveRS16(float* z, int ln) {
  int cnt = 16;
#pragma unroll
  for (int d = 2; d <= 16; d <<= 1) {
    int half = cnt >> 1;
    bool hi = (ln & d) != 0;
#pragma unroll
    for (int k = 0; k < 8; ++k) {
      if (k < half) {
        float a = z[k], b = z[half + k];
        z[k] = hi ? b : a;
        z[half + k] = hi ? a : b;
      }
    }
#pragma unroll
    for (int k = 0; k < 8; ++k)
      if (k < half) z[k] += __shfl_xor(z[half + k], d, 64);
    cnt = half;
  }
  return z[0] + __shfl_xor(z[0], 32, 64);
}

// --- Sinkhorn: 256 blocks x 1024 threads; 2 columns per block, slot-split ---
// One __syncthreads per iteration: zred is double-buffered (ping-pong per
// reduce) and every wave redundantly computes the u-update from the partials
// (identical order => bitwise-identical u across waves).
// __launch_bounds__(1024, 4): 4 waves/SIMD = 1 block/CU (what we run anyway),
// VGPR cap 128 — kr[] stays in registers instead of spilling (R12 lesson).
__global__ __launch_bounds__(1024, 4) void sinkhorn_kernel(
    const uint4* __restrict__ Kb, const float* __restrict__ KMt,
    const float* __restrict__ bT, const float* __restrict__ aT,
    unsigned* __restrict__ slots, float* __restrict__ outp) {
  const int t = threadIdx.x;
  const int w = t >> 6, ln = t & 63;   // 16 waves
  const int p = t & 1, pid = t >> 1;   // 512 pairs
  const int col0 = blockIdx.x << 1;
  const float* b0r = bT + (size_t)col0 * NV;
  const float* b1r = b0r + NV;
  float* accres = (float*)(slots + 64);
  unsigned* bar = slots + 65;

  __shared__ float zred[2][2][16][32];              // [buf][col][wave][slot]
  __shared__ __align__(16) float ushw[16 * 64];     // per-wave private u copy
  __shared__ float sredA[16], sredB[16];
  __shared__ unsigned ebits;
  __shared__ float vsh0[3072], vsh1[3072];
  __shared__ float bsh0[3072], bsh1[3072];

  // slot this lane owns after waveRS16
  const int sl = ((ln & 1) << 4) | ((ln & 2) << 2) | (ln & 4) |
                 ((ln & 8) >> 2) | ((ln & 16) >> 4);

  for (int idx = t; idx < NV; idx += 1024) { bsh0[idx] = b0r[idx]; bsh1[idx] = b1r[idx]; }
  // a[c][s] for this lane's (c,s) = (ln>>5, ln&31); same 64 values per wave.
  const float areg = aT[(size_t)col0 * 32 + ln];

  // pin K rows i<3 (v = pid, pid+512, pid+1024 — all < NV) in registers
  uint4 kr[6];
#pragma unroll
  for (int i = 0; i < 3; ++i) {
    const uint4* kq = Kb + ((size_t)(pid + (i << 9)) << 2) + (p << 1);
    kr[2 * i] = kq[0]; kr[2 * i + 1] = kq[1];
  }

  float2 u0[8], u1[8];
#pragma unroll
  for (int j = 0; j < 8; ++j) {
    u0[j] = make_float2(1.0f / 32.0f, 1.0f / 32.0f);
    u1[j] = make_float2(1.0f / 32.0f, 1.0f / 32.0f);
  }
  __syncthreads();  // bsh ready
  float err = 1.0f;
  int cpt = 0, chk = 0, zb = 0;
  unsigned barcnt = 0;

  // redundant per-wave u-update: read 16 partials for this lane's (c,s),
  // u = a*rcp(z); write wave-private slice; read back u0/u1 (within-wave
  // LDS ordering only — no barrier).
  auto ured = [&]() {
    int c = ln >> 5, s = ln & 31;
    float zz = 0.0f;
#pragma unroll
    for (int k = 0; k < 16; ++k) zz += zred[zb][c][k][s];
    float uu = areg * __builtin_amdgcn_rcpf(zz);
    ushw[(w << 6) + ln] = uu;
#pragma unroll
    for (int q = 0; q < 4; ++q) {
      *(float4*)((float*)u0 + q * 4) = *(float4*)(&ushw[(w << 6) + (p << 4) + q * 4]);
      *(float4*)((float*)u1 + q * 4) = *(float4*)(&ushw[(w << 6) + 32 + (p << 4) + q * 4]);
    }
    zb ^= 1;
  };

  while (cpt < 1000 && err > 0.005f) {
    float2 z0[8], z1[8];
#pragma unroll
    for (int j = 0; j < 8; ++j) { z0[j] = make_float2(0.0f, 0.0f); z1[j] = make_float2(0.0f, 0.0f); }
    kpass_ss<false>(Kb, kr, bsh0, bsh1, u0, u1, z0, z1, vsh0, vsh1, pid, p);
    float r0 = waveRS16((float*)z0, ln), r1 = waveRS16((float*)z1, ln);
    if (ln < 32) { zred[zb][0][w][sl] = r0; zred[zb][1][w][sl] = r1; }
    __syncthreads();
    ured();
    ++cpt;

    if (cpt % 20 == 1 || cpt == 1000) {
      // v = b/(K^T u) (store t into LDS); u = a/(K v)
#pragma unroll
      for (int j = 0; j < 8; ++j) { z0[j] = make_float2(0.0f, 0.0f); z1[j] = make_float2(0.0f, 0.0f); }
      kpass_ss<true>(Kb, kr, bsh0, bsh1, u0, u1, z0, z1, vsh0, vsh1, pid, p);
      r0 = waveRS16((float*)z0, ln); r1 = waveRS16((float*)z1, ln);
      if (ln < 32) { zred[zb][0][w][sl] = r0; zred[zb][1][w][sl] = r1; }
      __syncthreads();
      ured();
      float ep0 = 0.0f, ep1 = 0.0f;
      errpass_ss(Kb, kr, bsh0, bsh1, u0, u1, vsh0, vsh1, ep0, ep1, pid, p);
      ep0 = wave_sum(ep0); ep1 = wave_sum(ep1);
      if (ln == 0) { sredA[w] = ep0; sredB[w] = ep1; }
      __syncthreads();
      if (t == 0) {
        float e0 = 0.0f, e1 = 0.0f;
#pragma unroll
        for (int k = 0; k < 16; ++k) { e0 += sredA[k]; e1 += sredB[k]; }
        atomicMax(slots + chk, __float_as_uint(fmaxf(e0, e1)));
      }
      ++barcnt;
      gridbar(bar, barcnt * 256u);
      if (t == 0) ebits = __hip_atomic_load(slots + chk, __ATOMIC_RELAXED, __HIP_MEMORY_SCOPE_AGENT);
      __syncthreads();
      err = __uint_as_float(ebits);
      ++chk;
    }
  }

  // ---- epilogue: out_col = sum_s u[s] * sum_v KM[v][s]*t[v] ----
  float y0[16], y1[16];
#pragma unroll
  for (int s = 0; s < 16; ++s) { y0[s] = 0.0f; y1[s] = 0.0f; }
#pragma unroll
  for (int i = 0; i < 6; ++i) {
    int v = pid + (i << 9);
    if (i < 5 || v < NV) {
      const float4* kp = (const float4*)(KMt + (size_t)v * 32 + (p << 4));
      float kc[16];
#pragma unroll
      for (int q = 0; q < 4; ++q) *(float4*)(kc + q * 4) = kp[q];
      float x0 = vsh0[v], x1 = vsh1[v];
#pragma unroll
      for (int s = 0; s < 16; ++s) { y0[s] = fmaf(kc[s], x0, y0[s]); y1[s] = fmaf(kc[s], x1, y1[s]); }
    }
  }
  float r0 = waveRS16(y0, ln), r1 = waveRS16(y1, ln);
  __syncthreads();
  if (ln < 32) { zred[0][0][w][sl] = r0; zred[0][1][w][sl] = r1; }
  __syncthreads();
  if (t < 64) {
    int c = t >> 5, s = t & 31;
    float ys = 0.0f;
#pragma unroll
    for (int k = 0; k < 16; ++k) ys += zred[0][c][k][s];
    float pp = ys * ushw[t];  // wave 0's u copy (t<64 == wave 0)
#pragma unroll
    for (int off = 1; off <= 16; off <<= 1) pp += __shfl_xor(pp, off, 64);
    float other = __shfl_xor(pp, 32, 64);
    if (t == 0) atomicAdd(accres, pp + other);
  }
  ++barcnt;
  gridbar(bar, barcnt * 256u);
  if (blockIdx.x == 0 && t == 0) {
    unsigned ab = __hip_atomic_load((unsigned*)accres, __ATOMIC_RELAXED, __HIP_MEMORY_SCOPE_AGENT);
    outp[0] = __uint_as_float(ab) / 512.0f;
  }
}

// ---------------------------------------------------------------------------
extern "C" void kernel_launch(void* const* d_in, const int* in_sizes, int n_in,
                              void* d_out, int out_size, void* d_ws, size_t ws_size,
                              hipStream_t stream) {
  (void)in_sizes; (void)n_in; (void)out_size; (void)ws_size;
  const float* inputs  = (const float*)d_in[0];
  const float* outputs = (const float*)d_in[1];
  const float* W_lm    = (const float*)d_in[2];
  const float* W_lin   = (const float*)d_in[3];
  const float* b_lin   = (const float*)d_in[4];
  const float* topics  = (const float*)d_in[5];
  const int*   verbs   = (const int*)d_in[6];
  float* out = (float*)d_out;

  char* ws = (char*)d_ws;
  float*    L     = (float*)(ws);                 // 12,288,000 B (1024x3000)
  float*    L1    = L;                            //   rows 0..511 (becomes bT)
  float*    L2    = (float*)(ws + 6144000);       //   rows 512..1023
  float*    aT    = (float*)(ws + 12288000);      //     65,536 B
  unsigned* Kb    = (unsigned*)(ws + 12353536);   //    192,000 B (bf16 x2)
  float*    KMt   = (float*)(ws + 12545536);      //    384,000 B
  float*    topT  = (float*)(ws + 12929536);      //    131,072 B
  float*    vninv = (float*)(ws + 13060608);      //     12,032 B
  float*    tninv = (float*)(ws + 13072640);      //        128 B
  unsigned* slots = (unsigned*)(ws + 13072768);   //        512 B
  unsigned short* Xb = (unsigned short*)(ws + 13073280);  // 2,097,152 B
  unsigned short* Wb = (unsigned short*)(ws + 15170432);  // 6,291,456 B

  hipMemsetAsync((void*)slots, 0, 512, stream);

  norms_wb_kernel<<<3104, 256, 0, stream>>>(W_lm, topics, verbs, vninv, tninv, Wb);
  xb_kernel<<<512, 256, 0, stream>>>(inputs, Xb);
  topt_kernel<<<128, 256, 0, stream>>>(topics, tninv, topT);
  a_kernel<<<BB, 64, 0, stream>>>(outputs, W_lin, b_lin, aT);
  gemm_mfma<<<dim3(24, 8), 256, 0, stream>>>(Xb, Wb, L);
  softmax_kernel<<<BB, 256, 0, stream>>>(L1, L2);
  mk_kernel<<<47, 256, 0, stream>>>(W_lm, verbs, topT, vninv, Kb, KMt);
  sinkhorn_kernel<<<256, 1024, 0, stream>>>((const uint4*)Kb, KMt, /*bT=*/L1, aT, slots, out);
}

// Round 9
// 426.714 us; speedup vs baseline: 1.3368x; 1.3368x over previous
//
#include <hip/hip_runtime.h>

// ---------------------------------------------------------------------------
// lm_ot: LM softmax distributions + Sinkhorn OT, fused pipeline for MI355X.
// Sizes fixed by setup_inputs(): B=512, H=1024, V=28996, NV=3000, SLOTS=33.
// R14: R9 base + ONE-barrier iteration, SROA-safe. R12/R13's 98MB scratch was
//   NOT a VGPR-budget spill ((1024,4) cap=128 changed nothing, VGPR stayed
//   64): the ured LAMBDA captured u0/u1/kr arrays by reference (address
//   escape) -> failed SROA -> stack-homed arrays (~375B/thread, FETCH/WRITE
//   4.2x re-read). Fix: macro-inlined URED (no lambda), typed float2 u-loads
//   (no float4 punning), and kr-pinning dropped (unproven benefit, half the
//   stack blob). Design under test: zred ping-pong + redundant per-wave
//   u-update => 2 barriers/iter -> 1, no 960-threads-idle phase; identical
//   reduce order => bitwise-identical u.
// ---------------------------------------------------------------------------
#define NV 3000
#define HH 1024
#define BB 512

typedef __attribute__((ext_vector_type(8))) short short8;
typedef __attribute__((ext_vector_type(4))) float floatx4;

__device__ __forceinline__ float wave_sum(float x) {
#pragma unroll
  for (int off = 32; off; off >>= 1) x += __shfl_xor(x, off, 64);
  return x;
}
__device__ __forceinline__ unsigned bf16r(float x) {  // fp32 -> bf16 bits, RNE
  unsigned u = __float_as_uint(x);
  u += 0x7fffu + ((u >> 16) & 1u);
  return u >> 16;
}
__device__ __forceinline__ void gload16(const void* g, void* l) {
  // async global->LDS DMA; HW dst = wave-uniform base + lane*16B.
  __builtin_amdgcn_global_load_lds(
      (const __attribute__((address_space(1))) unsigned*)g,
      (__attribute__((address_space(3))) unsigned*)l, 16, 0, 0);
}

// packed 2xf32 fma: acc = a*b + acc (single VOP3P instruction)
__device__ __forceinline__ void pk_fma_acc(float2& acc, float2 a, float2 b) {
  asm("v_pk_fma_f32 %0, %1, %2, %0" : "+v"(acc) : "v"(a), "v"(b));
}
// unpack a packed-bf16 dword (lo = slot 2j, hi = slot 2j+1) to float2
__device__ __forceinline__ float2 unpk2(unsigned d) {
  float2 r;
  r.x = __uint_as_float(d << 16);
  r.y = __uint_as_float(d & 0xffff0000u);
  return r;
}

// --- norms of gathered W rows + topics, AND bf16 gather Wb[3072][1024] ------
__global__ __launch_bounds__(256) void norms_wb_kernel(
    const float* __restrict__ W_lm, const float* __restrict__ topics,
    const int* __restrict__ verbs, float* __restrict__ vninv,
    float* __restrict__ tninv, unsigned short* __restrict__ Wb) {
  int r = blockIdx.x, t = threadIdx.x;
  bool isW = r < 3072;
  int j = isW ? (r < NV ? r : NV - 1) : 0;
  const float* src = isW ? (W_lm + (size_t)verbs[j] * HH)
                         : (topics + (size_t)(r - 3072) * HH);
  float4 v = *(const float4*)(src + t * 4);
  if (isW) {
    *(uint2*)(Wb + (size_t)r * HH + t * 4) =
        make_uint2(bf16r(v.x) | (bf16r(v.y) << 16),
                   bf16r(v.z) | (bf16r(v.w) << 16));
  }
  float ss = v.x * v.x + v.y * v.y + v.z * v.z + v.w * v.w;
  ss = wave_sum(ss);
  __shared__ float sq[4];
  if ((t & 63) == 0) sq[t >> 6] = ss;
  __syncthreads();
  if (t == 0) {
    float inv = 1.0f / (sqrtf(sq[0] + sq[1] + sq[2] + sq[3]) + 1e-8f);
    if (isW) { if (r < NV) vninv[r] = inv; }
    else tninv[r - 3072] = inv;
  }
}

// --- Xb[1024][1024] bf16: rows 0..511 = inputs[:, :1024], 512.. = [:,1024:] -
__global__ __launch_bounds__(256) void xb_kernel(
    const float* __restrict__ inputs, unsigned short* __restrict__ Xb) {
  int idx = blockIdx.x * 256 + threadIdx.x;  // < 131072
  int r = idx >> 7, c8 = (idx & 127) << 3;
  const float* src = (r < 512) ? (inputs + (size_t)r * 2048 + c8)
                               : (inputs + (size_t)(r - 512) * 2048 + 1024 + c8);
  float4 x0 = ((const float4*)src)[0];
  float4 x1 = ((const float4*)src)[1];
  uint4 o;
  o.x = bf16r(x0.x) | (bf16r(x0.y) << 16);
  o.y = bf16r(x0.z) | (bf16r(x0.w) << 16);
  o.z = bf16r(x1.x) | (bf16r(x1.y) << 16);
  o.w = bf16r(x1.z) | (bf16r(x1.w) << 16);
  *(uint4*)(Xb + (size_t)r * HH + c8) = o;
}

// --- topT[k][s] = topics[s][k] * tninv[s]  (transposed+scaled, 1024x32) -----
__global__ __launch_bounds__(256) void topt_kernel(
    const float* __restrict__ topics, const float* __restrict__ tninv,
    float* __restrict__ topT) {
  int idx = blockIdx.x * 256 + threadIdx.x;  // = k*32 + s, < 32768
  int k = idx >> 5, s = idx & 31;
  topT[idx] = topics[(size_t)s * HH + k] * tninv[s];
}

// --- aT[row][0..31] = softmax((outputs @ W_lin^T + b_lin)[row, 1:33]) -------
__global__ __launch_bounds__(64) void a_kernel(
    const float* __restrict__ outputs, const float* __restrict__ W_lin,
    const float* __restrict__ b_lin, float* __restrict__ aT) {
  int r = blockIdx.x, t = threadIdx.x;
  __shared__ float orow[512];
  __shared__ float lg[33];
  __shared__ float ms[2];
  *(float4*)(orow + t * 8)     = *(const float4*)(outputs + (size_t)r * 512 + t * 8);
  *(float4*)(orow + t * 8 + 4) = *(const float4*)(outputs + (size_t)r * 512 + t * 8 + 4);
  __syncthreads();
  if (t < 33) {
    float acc = b_lin[t];
    for (int k = 0; k < 512; ++k) acc = fmaf(orow[k], W_lin[(size_t)t * 512 + k], acc);
    lg[t] = acc;
  }
  __syncthreads();
  if (t == 0) {
    float m = lg[1];
    for (int i = 2; i < 33; ++i) m = fmaxf(m, lg[i]);
    float ssum = 0.0f;
    for (int i = 1; i < 33; ++i) ssum += __expf(lg[i] - m);
    ms[0] = m; ms[1] = ssum;
  }
  __syncthreads();
  if (t >= 1 && t < 33) aT[(size_t)r * 32 + t - 1] = __expf(lg[t] - ms[0]) / ms[1];
}

// --- MFMA logits GEMM: L[1024][3000] = 0.5 * Xb @ Wb^T  (bf16 in, f32 out) --
__global__ __launch_bounds__(256) void gemm_mfma(
    const unsigned short* __restrict__ Xb, const unsigned short* __restrict__ Wb,
    float* __restrict__ L) {
  __shared__ unsigned short As[128 * 32], Bs[128 * 32];
  int t = threadIdx.x;
  int wave = t >> 6, ln = t & 63;
  int bn = blockIdx.x, bm = blockIdx.y;
  int wm = (wave >> 1) * 64, wn = (wave & 1) * 64;
  const unsigned short* ga = Xb + (size_t)(bm * 128 + (t >> 2)) * HH + (t & 3) * 8;
  const unsigned short* gb = Wb + (size_t)(bn * 128 + (t >> 2)) * HH + (t & 3) * 8;
  int lq = ln >> 4, lm = ln & 15;
  floatx4 acc[4][4];
#pragma unroll
  for (int i = 0; i < 4; ++i)
#pragma unroll
    for (int j = 0; j < 4; ++j) acc[i][j] = (floatx4)0.0f;

  for (int k0 = 0; k0 < HH; k0 += 32) {
    __syncthreads();
    gload16(ga + k0, As + t * 8);
    gload16(ga + (size_t)64 * HH + k0, As + 2048 + t * 8);
    gload16(gb + k0, Bs + t * 8);
    gload16(gb + (size_t)64 * HH + k0, Bs + 2048 + t * 8);
    __syncthreads();
    short8 af[4], bfr[4];
#pragma unroll
    for (int i = 0; i < 4; ++i)
      af[i] = *(const short8*)(As + (wm + i * 16 + lm) * 32 + lq * 8);
#pragma unroll
    for (int j = 0; j < 4; ++j)
      bfr[j] = *(const short8*)(Bs + (wn + j * 16 + lm) * 32 + lq * 8);
#pragma unroll
    for (int i = 0; i < 4; ++i)
#pragma unroll
      for (int j = 0; j < 4; ++j)
        acc[i][j] = __builtin_amdgcn_mfma_f32_16x16x32_bf16(af[i], bfr[j], acc[i][j], 0, 0, 0);
  }
  int row0 = bm * 128 + wm + lq * 4;
  int col0 = bn * 128 + wn + lm;
#pragma unroll
  for (int j = 0; j < 4; ++j) {
    int col = col0 + j * 16;
    if (col < NV) {
#pragma unroll
      for (int i = 0; i < 4; ++i) {
#pragma unroll
        for (int r = 0; r < 4; ++r)
          L[(size_t)(row0 + i * 16 + r) * NV + col] = acc[i][j][r] * 0.5f;
      }
    }
  }
}

// --- per-row: bT = renorm(0.5*(softmax(L1)+softmax(L2))), in-place over L1 ---
__global__ __launch_bounds__(256) void softmax_kernel(
    float* __restrict__ L1, const float* __restrict__ L2) {
  int r = blockIdx.x, t = threadIdx.x, w = t >> 6, ln = t & 63;
  float* row1 = L1 + (size_t)r * NV;
  const float* row2 = L2 + (size_t)r * NV;
  __shared__ float rd[2][4];
  float s1 = 0.0f, s2 = 0.0f;
  for (int v = t; v < NV; v += 256) { s1 += __expf(row1[v]); s2 += __expf(row2[v]); }
  s1 = wave_sum(s1); s2 = wave_sum(s2);
  if (ln == 0) { rd[0][w] = s1; rd[1][w] = s2; }
  __syncthreads();
  s1 = rd[0][0] + rd[0][1] + rd[0][2] + rd[0][3];
  s2 = rd[1][0] + rd[1][1] + rd[1][2] + rd[1][3];
  float i1 = 0.5f / s1, i2 = 0.5f / s2;
  float rs = 0.0f;
  for (int v = t; v < NV; v += 256) {
    float o = __expf(row1[v]) * i1 + __expf(row2[v]) * i2;
    row1[v] = o; rs += o;
  }
  rs = wave_sum(rs);
  __syncthreads();
  if (ln == 0) rd[0][w] = rs;
  __syncthreads();
  float rinv = 1.0f / (rd[0][0] + rd[0][1] + rd[0][2] + rd[0][3]);
  for (int v = t; v < NV; v += 256) row1[v] *= rinv;
}

// --- Kb[v][s]=bf16(exp(-20*M)) packed, KMt[v][s]=K*M fp32 ------------------
__global__ __launch_bounds__(256) void mk_kernel(
    const float* __restrict__ W_lm, const int* __restrict__ verbs,
    const float* __restrict__ topT, const float* __restrict__ vninv,
    unsigned* __restrict__ Kb, float* __restrict__ KMt) {
  __shared__ float red[4][64][33];
  int t = threadIdx.x, ln = t & 63, w = t >> 6;
  int v = blockIdx.x * 64 + ln;
  int vc = v < NV ? v : NV - 1;
  int kb = __builtin_amdgcn_readfirstlane(w) << 8;
  const float* wrow = W_lm + (size_t)verbs[vc] * HH + kb;
  const float* tb = topT + (size_t)kb * 32;
  float acc[32];
#pragma unroll
  for (int s = 0; s < 32; ++s) acc[s] = 0.0f;
  for (int kk = 0; kk < 256; kk += 4) {
    float4 w4 = *(const float4*)(wrow + kk);
    const float* tr = tb + kk * 32;
    const float* pw = (const float*)&w4;
#pragma unroll
    for (int d = 0; d < 4; ++d)
#pragma unroll
      for (int s = 0; s < 32; ++s) acc[s] = fmaf(pw[d], tr[d * 32 + s], acc[s]);
  }
#pragma unroll
  for (int s = 0; s < 32; ++s) red[w][ln][s] = acc[s];
  __syncthreads();
  for (int idx = t; idx < 1024; idx += 256) {
    int l = idx >> 4, pr = idx & 15;
    int vo = blockIdx.x * 64 + l;
    if (vo < NV) {
      int s0 = pr * 2, s1 = s0 + 1;
      float vi = vninv[vo];
      float d0 = red[0][l][s0] + red[1][l][s0] + red[2][l][s0] + red[3][l][s0];
      float d1 = red[0][l][s1] + red[1][l][s1] + red[2][l][s1] + red[3][l][s1];
      float M0 = 1.0f - d0 * vi, M1 = 1.0f - d1 * vi;
      float K0 = __expf(-20.0f * M0), K1 = __expf(-20.0f * M1);
      *(float2*)(KMt + (size_t)vo * 32 + s0) = make_float2(K0 * M0, K1 * M1);
      Kb[(size_t)vo * 16 + pr] = bf16r(K0) | (bf16r(K1) << 16);
    }
  }
}

// --- manual grid barrier: monotone counter, agent-scope atomics -------------
__device__ __forceinline__ void gridbar(unsigned* bar, unsigned target) {
  __syncthreads();
  if (threadIdx.x == 0) {
    __hip_atomic_fetch_add(bar, 1u, __ATOMIC_RELEASE, __HIP_MEMORY_SCOPE_AGENT);
    while (__hip_atomic_load(bar, __ATOMIC_ACQUIRE, __HIP_MEMORY_SCOPE_AGENT) < target) {
      __builtin_amdgcn_s_sleep(1);
    }
  }
  __syncthreads();
}

// slot-split fused pass: pair (2k,2k+1) shares each v-row; lane parity p owns
// slots [16p,16p+16). Full w rebuilt via shfl_xor(.,1). 512 pairs x 6 rows.
// K read from L2 each pass (R9-proven); inner math in v_pk_fma_f32.
template <bool STORE_T>
__device__ __forceinline__ void kpass_ss(
    const uint4* __restrict__ Kb, const float* __restrict__ bsh0,
    const float* __restrict__ bsh1, const float2* u0, const float2* u1,
    float2* z0, float2* z1, float* vsh0, float* vsh1, int pid, int p) {
#pragma unroll 3
  for (int i = 0; i < 6; ++i) {
    int v = pid + (i << 9);
    if (i < 5 || v < NV) {
      const uint4* kq = Kb + ((size_t)v << 2) + (p << 1);
      uint4 q0 = kq[0], q1 = kq[1];
      float2 kc[8];
      kc[0] = unpk2(q0.x); kc[1] = unpk2(q0.y);
      kc[2] = unpk2(q0.z); kc[3] = unpk2(q0.w);
      kc[4] = unpk2(q1.x); kc[5] = unpk2(q1.y);
      kc[6] = unpk2(q1.z); kc[7] = unpk2(q1.w);
      float2 w0 = make_float2(0.f, 0.f), w1 = make_float2(0.f, 0.f);
#pragma unroll
      for (int j = 0; j < 8; ++j) { pk_fma_acc(w0, kc[j], u0[j]); pk_fma_acc(w1, kc[j], u1[j]); }
      float s0 = w0.x + w0.y, s1 = w1.x + w1.y;
      s0 += __shfl_xor(s0, 1, 64);
      s1 += __shfl_xor(s1, 1, 64);
      float t0 = bsh0[v] * __builtin_amdgcn_rcpf(s0);
      float t1 = bsh1[v] * __builtin_amdgcn_rcpf(s1);
      if (STORE_T && !p) { vsh0[v] = t0; vsh1[v] = t1; }
      float2 t0p = make_float2(t0, t0), t1p = make_float2(t1, t1);
#pragma unroll
      for (int j = 0; j < 8; ++j) { pk_fma_acc(z0[j], kc[j], t0p); pk_fma_acc(z1[j], kc[j], t1p); }
    }
  }
}

__device__ __forceinline__ void errpass_ss(
    const uint4* __restrict__ Kb, const float* __restrict__ bsh0,
    const float* __restrict__ bsh1, const float2* u0, const float2* u1,
    const float* vsh0, const float* vsh1, float& ep0, float& ep1,
    int pid, int p) {
#pragma unroll 3
  for (int i = 0; i < 6; ++i) {
    int v = pid + (i << 9);
    if (i < 5 || v < NV) {
      const uint4* kq = Kb + ((size_t)v << 2) + (p << 1);
      uint4 q0 = kq[0], q1 = kq[1];
      float2 kc[8];
      kc[0] = unpk2(q0.x); kc[1] = unpk2(q0.y);
      kc[2] = unpk2(q0.z); kc[3] = unpk2(q0.w);
      kc[4] = unpk2(q1.x); kc[5] = unpk2(q1.y);
      kc[6] = unpk2(q1.z); kc[7] = unpk2(q1.w);
      float2 w0 = make_float2(0.f, 0.f), w1 = make_float2(0.f, 0.f);
#pragma unroll
      for (int j = 0; j < 8; ++j) { pk_fma_acc(w0, kc[j], u0[j]); pk_fma_acc(w1, kc[j], u1[j]); }
      float s0 = w0.x + w0.y, s1 = w1.x + w1.y;
      s0 += __shfl_xor(s0, 1, 64);
      s1 += __shfl_xor(s1, 1, 64);
      if (!p) {
        ep0 += fabsf(vsh0[v] * s0 - bsh0[v]);
        ep1 += fabsf(vsh1[v] * s1 - bsh1[v]);
      }
    }
  }
}

// 16-element reduce-scatter butterfly over strides 2..32 (parity classes stay
// separate). Lane ln ends holding the total of slot
// s = (ln&1)*16 + brev4((ln>>1)&15).
__device__ __forceinline__ float waveRS16(float* z, int ln) {
  int cnt = 16;
#pragma unroll
  for (int d = 2; d <= 16; d <<= 1) {
    int half = cnt >> 1;
    bool hi = (ln & d) != 0;
#pragma unroll
    for (int k = 0; k < 8; ++k) {
      if (k < half) {
        float a = z[k], b = z[half + k];
        z[k] = hi ? b : a;
        z[half + k] = hi ? a : b;
      }
    }
#pragma unroll
    for (int k = 0; k < 8; ++k)
      if (k < half) z[k] += __shfl_xor(z[half + k], d, 64);
    cnt = half;
  }
  return z[0] + __shfl_xor(z[0], 32, 64);
}

// redundant per-wave u-update (macro: no lambda, no address escape).
// Lane ln owns (c,s) = (ln>>5, ln&31); reads 16 partials from zred[zb],
// writes its wave-private ushw slice, reloads u0/u1 via typed float2 loads.
// Within-wave LDS ordering only — no barrier. Identical order across waves
// => bitwise-identical u. Toggles zb.
#define URED()                                                               \
  {                                                                          \
    int c_ = ln >> 5, s_ = ln & 31;                                          \
    float zz_ = 0.0f;                                                        \
    _Pragma("unroll") for (int k_ = 0; k_ < 16; ++k_)                        \
        zz_ += zred[zb][c_][k_][s_];                                         \
    float uu_ = areg * __builtin_amdgcn_rcpf(zz_);                           \
    ushw[(w << 6) + ln] = uu_;                                               \
    _Pragma("unroll") for (int j_ = 0; j_ < 8; ++j_) {                       \
      u0[j_] = *(const float2*)(&ushw[(w << 6) + (p << 4) + 2 * j_]);        \
      u1[j_] = *(const float2*)(&ushw[(w << 6) + 32 + (p << 4) + 2 * j_]);   \
    }                                                                        \
    zb ^= 1;                                                                 \
  }

// --- Sinkhorn: 256 blocks x 1024 threads; 2 columns per block, slot-split ---
// One __syncthreads per iteration: zred double-buffered; URED per wave.
__global__ __launch_bounds__(1024) void sinkhorn_kernel(
    const uint4* __restrict__ Kb, const float* __restrict__ KMt,
    const float* __restrict__ bT, const float* __restrict__ aT,
    unsigned* __restrict__ slots, float* __restrict__ outp) {
  const int t = threadIdx.x;
  const int w = t >> 6, ln = t & 63;   // 16 waves
  const int p = t & 1, pid = t >> 1;   // 512 pairs
  const int col0 = blockIdx.x << 1;
  const float* b0r = bT + (size_t)col0 * NV;
  const float* b1r = b0r + NV;
  float* accres = (float*)(slots + 64);
  unsigned* bar = slots + 65;

  __shared__ float zred[2][2][16][32];              // [buf][col][wave][slot]
  __shared__ __align__(16) float ushw[16 * 64];     // per-wave private u copy
  __shared__ float sredA[16], sredB[16];
  __shared__ unsigned ebits;
  __shared__ float vsh0[3072], vsh1[3072];
  __shared__ float bsh0[3072], bsh1[3072];

  // slot this lane owns after waveRS16
  const int sl = ((ln & 1) << 4) | ((ln & 2) << 2) | (ln & 4) |
                 ((ln & 8) >> 2) | ((ln & 16) >> 4);

  for (int idx = t; idx < NV; idx += 1024) { bsh0[idx] = b0r[idx]; bsh1[idx] = b1r[idx]; }
  // a[c][s] for this lane's (c,s) = (ln>>5, ln&31); same 64 values per wave.
  const float areg = aT[(size_t)col0 * 32 + ln];

  float2 u0[8], u1[8];
#pragma unroll
  for (int j = 0; j < 8; ++j) {
    u0[j] = make_float2(1.0f / 32.0f, 1.0f / 32.0f);
    u1[j] = make_float2(1.0f / 32.0f, 1.0f / 32.0f);
  }
  __syncthreads();  // bsh ready
  float err = 1.0f;
  int cpt = 0, chk = 0, zb = 0;
  unsigned barcnt = 0;

  while (cpt < 1000 && err > 0.005f) {
    float2 z0[8], z1[8];
#pragma unroll
    for (int j = 0; j < 8; ++j) { z0[j] = make_float2(0.0f, 0.0f); z1[j] = make_float2(0.0f, 0.0f); }
    kpass_ss<false>(Kb, bsh0, bsh1, u0, u1, z0, z1, vsh0, vsh1, pid, p);
    float r0 = waveRS16((float*)z0, ln), r1 = waveRS16((float*)z1, ln);
    if (ln < 32) { zred[zb][0][w][sl] = r0; zred[zb][1][w][sl] = r1; }
    __syncthreads();
    URED();
    ++cpt;

    if (cpt % 20 == 1 || cpt == 1000) {
      // v = b/(K^T u) (store t into LDS); u = a/(K v)
#pragma unroll
      for (int j = 0; j < 8; ++j) { z0[j] = make_float2(0.0f, 0.0f); z1[j] = make_float2(0.0f, 0.0f); }
      kpass_ss<true>(Kb, bsh0, bsh1, u0, u1, z0, z1, vsh0, vsh1, pid, p);
      r0 = waveRS16((float*)z0, ln); r1 = waveRS16((float*)z1, ln);
      if (ln < 32) { zred[zb][0][w][sl] = r0; zred[zb][1][w][sl] = r1; }
      __syncthreads();
      URED();
      float ep0 = 0.0f, ep1 = 0.0f;
      errpass_ss(Kb, bsh0, bsh1, u0, u1, vsh0, vsh1, ep0, ep1, pid, p);
      ep0 = wave_sum(ep0); ep1 = wave_sum(ep1);
      if (ln == 0) { sredA[w] = ep0; sredB[w] = ep1; }
      __syncthreads();
      if (t == 0) {
        float e0 = 0.0f, e1 = 0.0f;
#pragma unroll
        for (int k = 0; k < 16; ++k) { e0 += sredA[k]; e1 += sredB[k]; }
        atomicMax(slots + chk, __float_as_uint(fmaxf(e0, e1)));
      }
      ++barcnt;
      gridbar(bar, barcnt * 256u);
      if (t == 0) ebits = __hip_atomic_load(slots + chk, __ATOMIC_RELAXED, __HIP_MEMORY_SCOPE_AGENT);
      __syncthreads();
      err = __uint_as_float(ebits);
      ++chk;
    }
  }

  // ---- epilogue: out_col = sum_s u[s] * sum_v KM[v][s]*t[v] ----
  float y0[16], y1[16];
#pragma unroll
  for (int s = 0; s < 16; ++s) { y0[s] = 0.0f; y1[s] = 0.0f; }
#pragma unroll 3
  for (int i = 0; i < 6; ++i) {
    int v = pid + (i << 9);
    if (i < 5 || v < NV) {
      const float4* kp = (const float4*)(KMt + (size_t)v * 32 + (p << 4));
      float kc[16];
#pragma unroll
      for (int q = 0; q < 4; ++q) *(float4*)(kc + q * 4) = kp[q];
      float x0 = vsh0[v], x1 = vsh1[v];
#pragma unroll
      for (int s = 0; s < 16; ++s) { y0[s] = fmaf(kc[s], x0, y0[s]); y1[s] = fmaf(kc[s], x1, y1[s]); }
    }
  }
  float r0 = waveRS16(y0, ln), r1 = waveRS16(y1, ln);
  __syncthreads();
  if (ln < 32) { zred[0][0][w][sl] = r0; zred[0][1][w][sl] = r1; }
  __syncthreads();
  if (t < 64) {
    int c = t >> 5, s = t & 31;
    float ys = 0.0f;
#pragma unroll
    for (int k = 0; k < 16; ++k) ys += zred[0][c][k][s];
    float pp = ys * ushw[t];  // wave 0's u copy (t<64 == wave 0)
#pragma unroll
    for (int off = 1; off <= 16; off <<= 1) pp += __shfl_xor(pp, off, 64);
    float other = __shfl_xor(pp, 32, 64);
    if (t == 0) atomicAdd(accres, pp + other);
  }
  ++barcnt;
  gridbar(bar, barcnt * 256u);
  if (blockIdx.x == 0 && t == 0) {
    unsigned ab = __hip_atomic_load((unsigned*)accres, __ATOMIC_RELAXED, __HIP_MEMORY_SCOPE_AGENT);
    outp[0] = __uint_as_float(ab) / 512.0f;
  }
}

// ---------------------------------------------------------------------------
extern "C" void kernel_launch(void* const* d_in, const int* in_sizes, int n_in,
                              void* d_out, int out_size, void* d_ws, size_t ws_size,
                              hipStream_t stream) {
  (void)in_sizes; (void)n_in; (void)out_size; (void)ws_size;
  const float* inputs  = (const float*)d_in[0];
  const float* outputs = (const float*)d_in[1];
  const float* W_lm    = (const float*)d_in[2];
  const float* W_lin   = (const float*)d_in[3];
  const float* b_lin   = (const float*)d_in[4];
  const float* topics  = (const float*)d_in[5];
  const int*   verbs   = (const int*)d_in[6];
  float* out = (float*)d_out;

  char* ws = (char*)d_ws;
  float*    L     = (float*)(ws);                 // 12,288,000 B (1024x3000)
  float*    L1    = L;                            //   rows 0..511 (becomes bT)
  float*    L2    = (float*)(ws + 6144000);       //   rows 512..1023
  float*    aT    = (float*)(ws + 12288000);      //     65,536 B
  unsigned* Kb    = (unsigned*)(ws + 12353536);   //    192,000 B (bf16 x2)
  float*    KMt   = (float*)(ws + 12545536);      //    384,000 B
  float*    topT  = (float*)(ws + 12929536);      //    131,072 B
  float*    vninv = (float*)(ws + 13060608);      //     12,032 B
  float*    tninv = (float*)(ws + 13072640);      //        128 B
  unsigned* slots = (unsigned*)(ws + 13072768);   //        512 B
  unsigned short* Xb = (unsigned short*)(ws + 13073280);  // 2,097,152 B
  unsigned short* Wb = (unsigned short*)(ws + 15170432);  // 6,291,456 B

  hipMemsetAsync((void*)slots, 0, 512, stream);

  norms_wb_kernel<<<3104, 256, 0, stream>>>(W_lm, topics, verbs, vninv, tninv, Wb);
  xb_kernel<<<512, 256, 0, stream>>>(inputs, Xb);
  topt_kernel<<<128, 256, 0, stream>>>(topics, tninv, topT);
  a_kernel<<<BB, 64, 0, stream>>>(outputs, W_lin, b_lin, aT);
  gemm_mfma<<<dim3(24, 8), 256, 0, stream>>>(Xb, Wb, L);
  softmax_kernel<<<BB, 256, 0, stream>>>(L1, L2);
  mk_kernel<<<47, 256, 0, stream>>>(W_lm, verbs, topT, vninv, Kb, KMt);
  sinkhorn_kernel<<<256, 1024, 0, stream>>>((const uint4*)Kb, KMt, /*bT=*/L1, aT, slots, out);
}

// Round 10
// 385.931 us; speedup vs baseline: 1.4780x; 1.1057x over previous
//
#include <hip/hip_runtime.h>

// ---------------------------------------------------------------------------
// lm_ot: LM softmax distributions + Sinkhorn OT, fused pipeline for MI355X.
// Sizes fixed by setup_inputs(): B=512, H=1024, V=28996, NV=3000, SLOTS=33.
// R15: R9 body (176us, proven) + BLOCK-LOCAL convergence. After R9/R10/R14
//   exhausted intra-loop levers (instr cut neutral, K-LDS negative, barrier
//   cut neutral), the last unprobed cost is the grid-wide gridbar every 20
//   iters (~5-7us x 5-10 checks = 25-70us, invisible to VALUBusy: s_sleep).
//   Each block now stops on ITS 2 columns' err (columns are i.i.d.; near the
//   fixed point extra iterations move the output by O(err)=5e-3 x contraction
//   => expected absmax ~1e-4). In-loop gridbar + atomicMax deleted; final
//   accumulation via accres atomicAdd + done-counter (only block 0 waits).
//   DECLARED RISK: absmax leaves 0.0; if tolerance rejects, gridbar-free
//   stopping is dead and ~175us is the sinkhorn structural floor.
// ---------------------------------------------------------------------------
#define NV 3000
#define HH 1024
#define BB 512

typedef __attribute__((ext_vector_type(8))) short short8;
typedef __attribute__((ext_vector_type(4))) float floatx4;

__device__ __forceinline__ float wave_sum(float x) {
#pragma unroll
  for (int off = 32; off; off >>= 1) x += __shfl_xor(x, off, 64);
  return x;
}
__device__ __forceinline__ unsigned bf16r(float x) {  // fp32 -> bf16 bits, RNE
  unsigned u = __float_as_uint(x);
  u += 0x7fffu + ((u >> 16) & 1u);
  return u >> 16;
}
__device__ __forceinline__ void gload16(const void* g, void* l) {
  // async global->LDS DMA; HW dst = wave-uniform base + lane*16B.
  __builtin_amdgcn_global_load_lds(
      (const __attribute__((address_space(1))) unsigned*)g,
      (__attribute__((address_space(3))) unsigned*)l, 16, 0, 0);
}

// packed 2xf32 fma: acc = a*b + acc (single VOP3P instruction)
__device__ __forceinline__ void pk_fma_acc(float2& acc, float2 a, float2 b) {
  asm("v_pk_fma_f32 %0, %1, %2, %0" : "+v"(acc) : "v"(a), "v"(b));
}
// unpack a packed-bf16 dword (lo = slot 2j, hi = slot 2j+1) to float2
__device__ __forceinline__ float2 unpk2(unsigned d) {
  float2 r;
  r.x = __uint_as_float(d << 16);
  r.y = __uint_as_float(d & 0xffff0000u);
  return r;
}

// --- norms of gathered W rows + topics, AND bf16 gather Wb[3072][1024] ------
__global__ __launch_bounds__(256) void norms_wb_kernel(
    const float* __restrict__ W_lm, const float* __restrict__ topics,
    const int* __restrict__ verbs, float* __restrict__ vninv,
    float* __restrict__ tninv, unsigned short* __restrict__ Wb) {
  int r = blockIdx.x, t = threadIdx.x;
  bool isW = r < 3072;
  int j = isW ? (r < NV ? r : NV - 1) : 0;
  const float* src = isW ? (W_lm + (size_t)verbs[j] * HH)
                         : (topics + (size_t)(r - 3072) * HH);
  float4 v = *(const float4*)(src + t * 4);
  if (isW) {
    *(uint2*)(Wb + (size_t)r * HH + t * 4) =
        make_uint2(bf16r(v.x) | (bf16r(v.y) << 16),
                   bf16r(v.z) | (bf16r(v.w) << 16));
  }
  float ss = v.x * v.x + v.y * v.y + v.z * v.z + v.w * v.w;
  ss = wave_sum(ss);
  __shared__ float sq[4];
  if ((t & 63) == 0) sq[t >> 6] = ss;
  __syncthreads();
  if (t == 0) {
    float inv = 1.0f / (sqrtf(sq[0] + sq[1] + sq[2] + sq[3]) + 1e-8f);
    if (isW) { if (r < NV) vninv[r] = inv; }
    else tninv[r - 3072] = inv;
  }
}

// --- Xb[1024][1024] bf16: rows 0..511 = inputs[:, :1024], 512.. = [:,1024:] -
__global__ __launch_bounds__(256) void xb_kernel(
    const float* __restrict__ inputs, unsigned short* __restrict__ Xb) {
  int idx = blockIdx.x * 256 + threadIdx.x;  // < 131072
  int r = idx >> 7, c8 = (idx & 127) << 3;
  const float* src = (r < 512) ? (inputs + (size_t)r * 2048 + c8)
                               : (inputs + (size_t)(r - 512) * 2048 + 1024 + c8);
  float4 x0 = ((const float4*)src)[0];
  float4 x1 = ((const float4*)src)[1];
  uint4 o;
  o.x = bf16r(x0.x) | (bf16r(x0.y) << 16);
  o.y = bf16r(x0.z) | (bf16r(x0.w) << 16);
  o.z = bf16r(x1.x) | (bf16r(x1.y) << 16);
  o.w = bf16r(x1.z) | (bf16r(x1.w) << 16);
  *(uint4*)(Xb + (size_t)r * HH + c8) = o;
}

// --- topT[k][s] = topics[s][k] * tninv[s]  (transposed+scaled, 1024x32) -----
__global__ __launch_bounds__(256) void topt_kernel(
    const float* __restrict__ topics, const float* __restrict__ tninv,
    float* __restrict__ topT) {
  int idx = blockIdx.x * 256 + threadIdx.x;  // = k*32 + s, < 32768
  int k = idx >> 5, s = idx & 31;
  topT[idx] = topics[(size_t)s * HH + k] * tninv[s];
}

// --- aT[row][0..31] = softmax((outputs @ W_lin^T + b_lin)[row, 1:33]) -------
__global__ __launch_bounds__(64) void a_kernel(
    const float* __restrict__ outputs, const float* __restrict__ W_lin,
    const float* __restrict__ b_lin, float* __restrict__ aT) {
  int r = blockIdx.x, t = threadIdx.x;
  __shared__ float orow[512];
  __shared__ float lg[33];
  __shared__ float ms[2];
  *(float4*)(orow + t * 8)     = *(const float4*)(outputs + (size_t)r * 512 + t * 8);
  *(float4*)(orow + t * 8 + 4) = *(const float4*)(outputs + (size_t)r * 512 + t * 8 + 4);
  __syncthreads();
  if (t < 33) {
    float acc = b_lin[t];
    for (int k = 0; k < 512; ++k) acc = fmaf(orow[k], W_lin[(size_t)t * 512 + k], acc);
    lg[t] = acc;
  }
  __syncthreads();
  if (t == 0) {
    float m = lg[1];
    for (int i = 2; i < 33; ++i) m = fmaxf(m, lg[i]);
    float ssum = 0.0f;
    for (int i = 1; i < 33; ++i) ssum += __expf(lg[i] - m);
    ms[0] = m; ms[1] = ssum;
  }
  __syncthreads();
  if (t >= 1 && t < 33) aT[(size_t)r * 32 + t - 1] = __expf(lg[t] - ms[0]) / ms[1];
}

// --- MFMA logits GEMM: L[1024][3000] = 0.5 * Xb @ Wb^T  (bf16 in, f32 out) --
__global__ __launch_bounds__(256) void gemm_mfma(
    const unsigned short* __restrict__ Xb, const unsigned short* __restrict__ Wb,
    float* __restrict__ L) {
  __shared__ unsigned short As[128 * 32], Bs[128 * 32];
  int t = threadIdx.x;
  int wave = t >> 6, ln = t & 63;
  int bn = blockIdx.x, bm = blockIdx.y;
  int wm = (wave >> 1) * 64, wn = (wave & 1) * 64;
  const unsigned short* ga = Xb + (size_t)(bm * 128 + (t >> 2)) * HH + (t & 3) * 8;
  const unsigned short* gb = Wb + (size_t)(bn * 128 + (t >> 2)) * HH + (t & 3) * 8;
  int lq = ln >> 4, lm = ln & 15;
  floatx4 acc[4][4];
#pragma unroll
  for (int i = 0; i < 4; ++i)
#pragma unroll
    for (int j = 0; j < 4; ++j) acc[i][j] = (floatx4)0.0f;

  for (int k0 = 0; k0 < HH; k0 += 32) {
    __syncthreads();
    gload16(ga + k0, As + t * 8);
    gload16(ga + (size_t)64 * HH + k0, As + 2048 + t * 8);
    gload16(gb + k0, Bs + t * 8);
    gload16(gb + (size_t)64 * HH + k0, Bs + 2048 + t * 8);
    __syncthreads();
    short8 af[4], bfr[4];
#pragma unroll
    for (int i = 0; i < 4; ++i)
      af[i] = *(const short8*)(As + (wm + i * 16 + lm) * 32 + lq * 8);
#pragma unroll
    for (int j = 0; j < 4; ++j)
      bfr[j] = *(const short8*)(Bs + (wn + j * 16 + lm) * 32 + lq * 8);
#pragma unroll
    for (int i = 0; i < 4; ++i)
#pragma unroll
      for (int j = 0; j < 4; ++j)
        acc[i][j] = __builtin_amdgcn_mfma_f32_16x16x32_bf16(af[i], bfr[j], acc[i][j], 0, 0, 0);
  }
  int row0 = bm * 128 + wm + lq * 4;
  int col0 = bn * 128 + wn + lm;
#pragma unroll
  for (int j = 0; j < 4; ++j) {
    int col = col0 + j * 16;
    if (col < NV) {
#pragma unroll
      for (int i = 0; i < 4; ++i) {
#pragma unroll
        for (int r = 0; r < 4; ++r)
          L[(size_t)(row0 + i * 16 + r) * NV + col] = acc[i][j][r] * 0.5f;
      }
    }
  }
}

// --- per-row: bT = renorm(0.5*(softmax(L1)+softmax(L2))), in-place over L1 ---
__global__ __launch_bounds__(256) void softmax_kernel(
    float* __restrict__ L1, const float* __restrict__ L2) {
  int r = blockIdx.x, t = threadIdx.x, w = t >> 6, ln = t & 63;
  float* row1 = L1 + (size_t)r * NV;
  const float* row2 = L2 + (size_t)r * NV;
  __shared__ float rd[2][4];
  float s1 = 0.0f, s2 = 0.0f;
  for (int v = t; v < NV; v += 256) { s1 += __expf(row1[v]); s2 += __expf(row2[v]); }
  s1 = wave_sum(s1); s2 = wave_sum(s2);
  if (ln == 0) { rd[0][w] = s1; rd[1][w] = s2; }
  __syncthreads();
  s1 = rd[0][0] + rd[0][1] + rd[0][2] + rd[0][3];
  s2 = rd[1][0] + rd[1][1] + rd[1][2] + rd[1][3];
  float i1 = 0.5f / s1, i2 = 0.5f / s2;
  float rs = 0.0f;
  for (int v = t; v < NV; v += 256) {
    float o = __expf(row1[v]) * i1 + __expf(row2[v]) * i2;
    row1[v] = o; rs += o;
  }
  rs = wave_sum(rs);
  __syncthreads();
  if (ln == 0) rd[0][w] = rs;
  __syncthreads();
  float rinv = 1.0f / (rd[0][0] + rd[0][1] + rd[0][2] + rd[0][3]);
  for (int v = t; v < NV; v += 256) row1[v] *= rinv;
}

// --- Kb[v][s]=bf16(exp(-20*M)) packed, KMt[v][s]=K*M fp32 ------------------
__global__ __launch_bounds__(256) void mk_kernel(
    const float* __restrict__ W_lm, const int* __restrict__ verbs,
    const float* __restrict__ topT, const float* __restrict__ vninv,
    unsigned* __restrict__ Kb, float* __restrict__ KMt) {
  __shared__ float red[4][64][33];
  int t = threadIdx.x, ln = t & 63, w = t >> 6;
  int v = blockIdx.x * 64 + ln;
  int vc = v < NV ? v : NV - 1;
  int kb = __builtin_amdgcn_readfirstlane(w) << 8;
  const float* wrow = W_lm + (size_t)verbs[vc] * HH + kb;
  const float* tb = topT + (size_t)kb * 32;
  float acc[32];
#pragma unroll
  for (int s = 0; s < 32; ++s) acc[s] = 0.0f;
  for (int kk = 0; kk < 256; kk += 4) {
    float4 w4 = *(const float4*)(wrow + kk);
    const float* tr = tb + kk * 32;
    const float* pw = (const float*)&w4;
#pragma unroll
    for (int d = 0; d < 4; ++d)
#pragma unroll
      for (int s = 0; s < 32; ++s) acc[s] = fmaf(pw[d], tr[d * 32 + s], acc[s]);
  }
#pragma unroll
  for (int s = 0; s < 32; ++s) red[w][ln][s] = acc[s];
  __syncthreads();
  for (int idx = t; idx < 1024; idx += 256) {
    int l = idx >> 4, pr = idx & 15;
    int vo = blockIdx.x * 64 + l;
    if (vo < NV) {
      int s0 = pr * 2, s1 = s0 + 1;
      float vi = vninv[vo];
      float d0 = red[0][l][s0] + red[1][l][s0] + red[2][l][s0] + red[3][l][s0];
      float d1 = red[0][l][s1] + red[1][l][s1] + red[2][l][s1] + red[3][l][s1];
      float M0 = 1.0f - d0 * vi, M1 = 1.0f - d1 * vi;
      float K0 = __expf(-20.0f * M0), K1 = __expf(-20.0f * M1);
      *(float2*)(KMt + (size_t)vo * 32 + s0) = make_float2(K0 * M0, K1 * M1);
      Kb[(size_t)vo * 16 + pr] = bf16r(K0) | (bf16r(K1) << 16);
    }
  }
}

// slot-split fused pass: pair (2k,2k+1) shares each v-row; lane parity p owns
// slots [16p,16p+16). Full w rebuilt via shfl_xor(.,1). 512 pairs x 6 rows.
// K read from L2 each pass (R9-proven); inner math in v_pk_fma_f32.
template <bool STORE_T>
__device__ __forceinline__ void kpass_ss(
    const uint4* __restrict__ Kb, const float* __restrict__ bsh0,
    const float* __restrict__ bsh1, const float2* u0, const float2* u1,
    float2* z0, float2* z1, float* vsh0, float* vsh1, int pid, int p) {
#pragma unroll 3
  for (int i = 0; i < 6; ++i) {
    int v = pid + (i << 9);
    if (i < 5 || v < NV) {
      const uint4* kq = Kb + ((size_t)v << 2) + (p << 1);
      uint4 q0 = kq[0], q1 = kq[1];
      float2 kc[8];
      kc[0] = unpk2(q0.x); kc[1] = unpk2(q0.y);
      kc[2] = unpk2(q0.z); kc[3] = unpk2(q0.w);
      kc[4] = unpk2(q1.x); kc[5] = unpk2(q1.y);
      kc[6] = unpk2(q1.z); kc[7] = unpk2(q1.w);
      float2 w0 = make_float2(0.f, 0.f), w1 = make_float2(0.f, 0.f);
#pragma unroll
      for (int j = 0; j < 8; ++j) { pk_fma_acc(w0, kc[j], u0[j]); pk_fma_acc(w1, kc[j], u1[j]); }
      float s0 = w0.x + w0.y, s1 = w1.x + w1.y;
      s0 += __shfl_xor(s0, 1, 64);
      s1 += __shfl_xor(s1, 1, 64);
      float t0 = bsh0[v] * __builtin_amdgcn_rcpf(s0);
      float t1 = bsh1[v] * __builtin_amdgcn_rcpf(s1);
      if (STORE_T && !p) { vsh0[v] = t0; vsh1[v] = t1; }
      float2 t0p = make_float2(t0, t0), t1p = make_float2(t1, t1);
#pragma unroll
      for (int j = 0; j < 8; ++j) { pk_fma_acc(z0[j], kc[j], t0p); pk_fma_acc(z1[j], kc[j], t1p); }
    }
  }
}

__device__ __forceinline__ void errpass_ss(
    const uint4* __restrict__ Kb, const float* __restrict__ bsh0,
    const float* __restrict__ bsh1, const float2* u0, const float2* u1,
    const float* vsh0, const float* vsh1, float& ep0, float& ep1,
    int pid, int p) {
#pragma unroll 3
  for (int i = 0; i < 6; ++i) {
    int v = pid + (i << 9);
    if (i < 5 || v < NV) {
      const uint4* kq = Kb + ((size_t)v << 2) + (p << 1);
      uint4 q0 = kq[0], q1 = kq[1];
      float2 kc[8];
      kc[0] = unpk2(q0.x); kc[1] = unpk2(q0.y);
      kc[2] = unpk2(q0.z); kc[3] = unpk2(q0.w);
      kc[4] = unpk2(q1.x); kc[5] = unpk2(q1.y);
      kc[6] = unpk2(q1.z); kc[7] = unpk2(q1.w);
      float2 w0 = make_float2(0.f, 0.f), w1 = make_float2(0.f, 0.f);
#pragma unroll
      for (int j = 0; j < 8; ++j) { pk_fma_acc(w0, kc[j], u0[j]); pk_fma_acc(w1, kc[j], u1[j]); }
      float s0 = w0.x + w0.y, s1 = w1.x + w1.y;
      s0 += __shfl_xor(s0, 1, 64);
      s1 += __shfl_xor(s1, 1, 64);
      if (!p) {
        ep0 += fabsf(vsh0[v] * s0 - bsh0[v]);
        ep1 += fabsf(vsh1[v] * s1 - bsh1[v]);
      }
    }
  }
}

// 16-element reduce-scatter butterfly over strides 2..32 (parity classes stay
// separate). Lane ln ends holding the total of slot
// s = (ln&1)*16 + brev4((ln>>1)&15).
__device__ __forceinline__ float waveRS16(float* z, int ln) {
  int cnt = 16;
#pragma unroll
  for (int d = 2; d <= 16; d <<= 1) {
    int half = cnt >> 1;
    bool hi = (ln & d) != 0;
#pragma unroll
    for (int k = 0; k < 8; ++k) {
      if (k < half) {
        float a = z[k], b = z[half + k];
        z[k] = hi ? b : a;
        z[half + k] = hi ? a : b;
      }
    }
#pragma unroll
    for (int k = 0; k < 8; ++k)
      if (k < half) z[k] += __shfl_xor(z[half + k], d, 64);
    cnt = half;
  }
  return z[0] + __shfl_xor(z[0], 32, 64);
}

// --- Sinkhorn: 256 blocks x 1024 threads; 2 columns per block, slot-split ---
// Block-local convergence: no in-loop grid sync. Final accumulation via
// accres atomicAdd + done-counter; only block 0 waits for all 256.
__global__ __launch_bounds__(1024) void sinkhorn_kernel(
    const uint4* __restrict__ Kb, const float* __restrict__ KMt,
    const float* __restrict__ bT, const float* __restrict__ aT,
    unsigned* __restrict__ slots, float* __restrict__ outp) {
  const int t = threadIdx.x;
  const int w = t >> 6, ln = t & 63;   // 16 waves
  const int p = t & 1, pid = t >> 1;   // 512 pairs
  const int col0 = blockIdx.x << 1;
  const float* b0r = bT + (size_t)col0 * NV;
  const float* b1r = b0r + NV;
  float* accres = (float*)(slots + 64);
  unsigned* done = slots + 65;

  __shared__ float zred[2][16][32];
  __shared__ float ush[2][32];
  __shared__ float sredA[16], sredB[16];
  __shared__ unsigned ebits;
  __shared__ float vsh0[3072], vsh1[3072];
  __shared__ float bsh0[3072], bsh1[3072];
  float* ushf = &ush[0][0];

  // slot this lane owns after waveRS16
  const int sl = ((ln & 1) << 4) | ((ln & 2) << 2) | (ln & 4) |
                 ((ln & 8) >> 2) | ((ln & 16) >> 4);

  for (int idx = t; idx < NV; idx += 1024) { bsh0[idx] = b0r[idx]; bsh1[idx] = b1r[idx]; }
  float areg = (t < 64) ? aT[(size_t)col0 * 32 + t] : 0.0f;

  float2 u0[8], u1[8];
#pragma unroll
  for (int j = 0; j < 8; ++j) {
    u0[j] = make_float2(1.0f / 32.0f, 1.0f / 32.0f);
    u1[j] = make_float2(1.0f / 32.0f, 1.0f / 32.0f);
  }
  if (t < 64) ushf[t] = 1.0f / 32.0f;
  __syncthreads();  // bsh ready
  float err = 1.0f;
  int cpt = 0;

  while (cpt < 1000 && err > 0.005f) {
    float2 z0[8], z1[8];
#pragma unroll
    for (int j = 0; j < 8; ++j) { z0[j] = make_float2(0.0f, 0.0f); z1[j] = make_float2(0.0f, 0.0f); }
    kpass_ss<false>(Kb, bsh0, bsh1, u0, u1, z0, z1, vsh0, vsh1, pid, p);
    float r0 = waveRS16((float*)z0, ln), r1 = waveRS16((float*)z1, ln);
    __syncthreads();
    if (ln < 32) { zred[0][w][sl] = r0; zred[1][w][sl] = r1; }
    __syncthreads();
    if (t < 64) {
      int c = t >> 5, s = t & 31;
      float zz = 0.0f;
#pragma unroll
      for (int k = 0; k < 16; ++k) zz += zred[c][k][s];
      ushf[t] = areg * __builtin_amdgcn_rcpf(zz);
    }
    __syncthreads();
#pragma unroll
    for (int q = 0; q < 4; ++q) {
      *(float4*)((float*)u0 + q * 4) = *(float4*)(&ush[0][(p << 4) + q * 4]);
      *(float4*)((float*)u1 + q * 4) = *(float4*)(&ush[1][(p << 4) + q * 4]);
    }
    ++cpt;

    if (cpt % 20 == 1 || cpt == 1000) {
      // v = b/(K^T u) (store t into LDS); u = a/(K v)
#pragma unroll
      for (int j = 0; j < 8; ++j) { z0[j] = make_float2(0.0f, 0.0f); z1[j] = make_float2(0.0f, 0.0f); }
      kpass_ss<true>(Kb, bsh0, bsh1, u0, u1, z0, z1, vsh0, vsh1, pid, p);
      r0 = waveRS16((float*)z0, ln); r1 = waveRS16((float*)z1, ln);
      __syncthreads();
      if (ln < 32) { zred[0][w][sl] = r0; zred[1][w][sl] = r1; }
      __syncthreads();
      if (t < 64) {
        int c = t >> 5, s = t & 31;
        float zz = 0.0f;
#pragma unroll
        for (int k = 0; k < 16; ++k) zz += zred[c][k][s];
        ushf[t] = areg * __builtin_amdgcn_rcpf(zz);
      }
      __syncthreads();
#pragma unroll
      for (int q = 0; q < 4; ++q) {
        *(float4*)((float*)u0 + q * 4) = *(float4*)(&ush[0][(p << 4) + q * 4]);
        *(float4*)((float*)u1 + q * 4) = *(float4*)(&ush[1][(p << 4) + q * 4]);
      }
      float ep0 = 0.0f, ep1 = 0.0f;
      errpass_ss(Kb, bsh0, bsh1, u0, u1, vsh0, vsh1, ep0, ep1, pid, p);
      ep0 = wave_sum(ep0); ep1 = wave_sum(ep1);
      if (ln == 0) { sredA[w] = ep0; sredB[w] = ep1; }
      __syncthreads();
      if (t == 0) {
        float e0 = 0.0f, e1 = 0.0f;
#pragma unroll
        for (int k = 0; k < 16; ++k) { e0 += sredA[k]; e1 += sredB[k]; }
        ebits = __float_as_uint(fmaxf(e0, e1));  // block-local err
      }
      __syncthreads();
      err = __uint_as_float(ebits);
    }
  }

  // ---- epilogue: out_col = sum_s u[s] * sum_v KM[v][s]*t[v] ----
  float y0[16], y1[16];
#pragma unroll
  for (int s = 0; s < 16; ++s) { y0[s] = 0.0f; y1[s] = 0.0f; }
#pragma unroll 3
  for (int i = 0; i < 6; ++i) {
    int v = pid + (i << 9);
    if (i < 5 || v < NV) {
      const float4* kp = (const float4*)(KMt + (size_t)v * 32 + (p << 4));
      float kc[16];
#pragma unroll
      for (int q = 0; q < 4; ++q) *(float4*)(kc + q * 4) = kp[q];
      float x0 = vsh0[v], x1 = vsh1[v];
#pragma unroll
      for (int s = 0; s < 16; ++s) { y0[s] = fmaf(kc[s], x0, y0[s]); y1[s] = fmaf(kc[s], x1, y1[s]); }
    }
  }
  float r0 = waveRS16(y0, ln), r1 = waveRS16(y1, ln);
  __syncthreads();
  if (ln < 32) { zred[0][w][sl] = r0; zred[1][w][sl] = r1; }
  __syncthreads();
  if (t < 64) {
    int c = t >> 5, s = t & 31;
    float ys = 0.0f;
#pragma unroll
    for (int k = 0; k < 16; ++k) ys += zred[c][k][s];
    float pp = ys * ushf[t];
#pragma unroll
    for (int off = 1; off <= 16; off <<= 1) pp += __shfl_xor(pp, off, 64);
    float other = __shfl_xor(pp, 32, 64);
    if (t == 0) {
      atomicAdd(accres, pp + other);
      // release: make accres add visible before done-count increment
      __hip_atomic_fetch_add(done, 1u, __ATOMIC_RELEASE, __HIP_MEMORY_SCOPE_AGENT);
    }
  }
  if (blockIdx.x == 0 && t == 0) {
    while (__hip_atomic_load(done, __ATOMIC_ACQUIRE, __HIP_MEMORY_SCOPE_AGENT) < 256u) {
      __builtin_amdgcn_s_sleep(1);
    }
    unsigned ab = __hip_atomic_load((unsigned*)accres, __ATOMIC_RELAXED, __HIP_MEMORY_SCOPE_AGENT);
    outp[0] = __uint_as_float(ab) / 512.0f;
  }
}

// ---------------------------------------------------------------------------
extern "C" void kernel_launch(void* const* d_in, const int* in_sizes, int n_in,
                              void* d_out, int out_size, void* d_ws, size_t ws_size,
                              hipStream_t stream) {
  (void)in_sizes; (void)n_in; (void)out_size; (void)ws_size;
  const float* inputs  = (const float*)d_in[0];
  const float* outputs = (const float*)d_in[1];
  const float* W_lm    = (const float*)d_in[2];
  const float* W_lin   = (const float*)d_in[3];
  const float* b_lin   = (const float*)d_in[4];
  const float* topics  = (const float*)d_in[5];
  const int*   verbs   = (const int*)d_in[6];
  float* out = (float*)d_out;

  char* ws = (char*)d_ws;
  float*    L     = (float*)(ws);                 // 12,288,000 B (1024x3000)
  float*    L1    = L;                            //   rows 0..511 (becomes bT)
  float*    L2    = (float*)(ws + 6144000);       //   rows 512..1023
  float*    aT    = (float*)(ws + 12288000);      //     65,536 B
  unsigned* Kb    = (unsigned*)(ws + 12353536);   //    192,000 B (bf16 x2)
  float*    KMt   = (float*)(ws + 12545536);      //    384,000 B
  float*    topT  = (float*)(ws + 12929536);      //    131,072 B
  float*    vninv = (float*)(ws + 13060608);      //     12,032 B
  float*    tninv = (float*)(ws + 13072640);      //        128 B
  unsigned* slots = (unsigned*)(ws + 13072768);   //        512 B
  unsigned short* Xb = (unsigned short*)(ws + 13073280);  // 2,097,152 B
  unsigned short* Wb = (unsigned short*)(ws + 15170432);  // 6,291,456 B

  hipMemsetAsync((void*)slots, 0, 512, stream);

  norms_wb_kernel<<<3104, 256, 0, stream>>>(W_lm, topics, verbs, vninv, tninv, Wb);
  xb_kernel<<<512, 256, 0, stream>>>(inputs, Xb);
  topt_kernel<<<128, 256, 0, stream>>>(topics, tninv, topT);
  a_kernel<<<BB, 64, 0, stream>>>(outputs, W_lin, b_lin, aT);
  gemm_mfma<<<dim3(24, 8), 256, 0, stream>>>(Xb, Wb, L);
  softmax_kernel<<<BB, 256, 0, stream>>>(L1, L2);
  mk_kernel<<<47, 256, 0, stream>>>(W_lm, verbs, topT, vninv, Kb, KMt);
  sinkhorn_kernel<<<256, 1024, 0, stream>>>((const uint4*)Kb, KMt, /*bT=*/L1, aT, slots, out);
}

// Round 11
// 370.942 us; speedup vs baseline: 1.5377x; 1.0404x over previous
//
#include <hip/hip_runtime.h>

// ---------------------------------------------------------------------------
// lm_ot: LM softmax distributions + Sinkhorn OT, fused pipeline for MI355X.
// Sizes fixed by setup_inputs(): B=512, H=1024, V=28996, NV=3000, SLOTS=33.
// R16: pipeline collapse. R15 proved sinkhorn=137us but e2e-sinkhorn ~249us
//   (stable across all rounds) — the 8-launch pipeline now dominates.
//   (1) softmax_kernel fused into sinkhorn prologue (block b owns exactly bT
//       rows 2b,2b+1): waves 0-3 row0 / 8-11 row1 replicate the old 256-thr
//       stride + wave_sum + rd[4] order BITWISE; exp stored in bsh/vsh
//       scratch; L write/re-read round trip eliminated.
//   (2) a_kernel fused: waves 4/6 replicate the old 64-thr serial-dot block
//       (same fmaf order, same serial max/ssum) -> ash in LDS. Bitwise same.
//   (3) norms_wb+xb -> prep_kernel; topt+gemm -> gt_kernel (topt reads tninv
//       from prep — prior launch). 8 launches -> 5.
//   Sinkhorn loop/epilogue = R15 verbatim (block-local convergence, 137us).
// ---------------------------------------------------------------------------
#define NV 3000
#define HH 1024
#define BB 512

typedef __attribute__((ext_vector_type(8))) short short8;
typedef __attribute__((ext_vector_type(4))) float floatx4;

__device__ __forceinline__ float wave_sum(float x) {
#pragma unroll
  for (int off = 32; off; off >>= 1) x += __shfl_xor(x, off, 64);
  return x;
}
__device__ __forceinline__ unsigned bf16r(float x) {  // fp32 -> bf16 bits, RNE
  unsigned u = __float_as_uint(x);
  u += 0x7fffu + ((u >> 16) & 1u);
  return u >> 16;
}
__device__ __forceinline__ void gload16(const void* g, void* l) {
  // async global->LDS DMA; HW dst = wave-uniform base + lane*16B.
  __builtin_amdgcn_global_load_lds(
      (const __attribute__((address_space(1))) unsigned*)g,
      (__attribute__((address_space(3))) unsigned*)l, 16, 0, 0);
}

// packed 2xf32 fma: acc = a*b + acc (single VOP3P instruction)
__device__ __forceinline__ void pk_fma_acc(float2& acc, float2 a, float2 b) {
  asm("v_pk_fma_f32 %0, %1, %2, %0" : "+v"(acc) : "v"(a), "v"(b));
}
// unpack a packed-bf16 dword (lo = slot 2j, hi = slot 2j+1) to float2
__device__ __forceinline__ float2 unpk2(unsigned d) {
  float2 r;
  r.x = __uint_as_float(d << 16);
  r.y = __uint_as_float(d & 0xffff0000u);
  return r;
}

// --- prep: r<3104 = norms of gathered W rows + topics + bf16 Wb gather;
//           r>=3104 = Xb[1024][1024] build. Bodies verbatim from R15. -------
__global__ __launch_bounds__(256) void prep_kernel(
    const float* __restrict__ W_lm, const float* __restrict__ topics,
    const int* __restrict__ verbs, float* __restrict__ vninv,
    float* __restrict__ tninv, unsigned short* __restrict__ Wb,
    const float* __restrict__ inputs, unsigned short* __restrict__ Xb) {
  __shared__ float sq[4];
  int rb = blockIdx.x, t = threadIdx.x;
  if (rb >= 3104) {
    int idx = (rb - 3104) * 256 + t;  // < 131072
    int r = idx >> 7, c8 = (idx & 127) << 3;
    const float* src = (r < 512) ? (inputs + (size_t)r * 2048 + c8)
                                 : (inputs + (size_t)(r - 512) * 2048 + 1024 + c8);
    float4 x0 = ((const float4*)src)[0];
    float4 x1 = ((const float4*)src)[1];
    uint4 o;
    o.x = bf16r(x0.x) | (bf16r(x0.y) << 16);
    o.y = bf16r(x0.z) | (bf16r(x0.w) << 16);
    o.z = bf16r(x1.x) | (bf16r(x1.y) << 16);
    o.w = bf16r(x1.z) | (bf16r(x1.w) << 16);
    *(uint4*)(Xb + (size_t)r * HH + c8) = o;
    return;
  }
  int r = rb;
  bool isW = r < 3072;
  int j = isW ? (r < NV ? r : NV - 1) : 0;
  const float* src = isW ? (W_lm + (size_t)verbs[j] * HH)
                         : (topics + (size_t)(r - 3072) * HH);
  float4 v = *(const float4*)(src + t * 4);
  if (isW) {
    *(uint2*)(Wb + (size_t)r * HH + t * 4) =
        make_uint2(bf16r(v.x) | (bf16r(v.y) << 16),
                   bf16r(v.z) | (bf16r(v.w) << 16));
  }
  float ss = v.x * v.x + v.y * v.y + v.z * v.z + v.w * v.w;
  ss = wave_sum(ss);
  if ((t & 63) == 0) sq[t >> 6] = ss;
  __syncthreads();
  if (t == 0) {
    float inv = 1.0f / (sqrtf(sq[0] + sq[1] + sq[2] + sq[3]) + 1e-8f);
    if (isW) { if (r < NV) vninv[r] = inv; }
    else tninv[r - 3072] = inv;
  }
}

// --- gt: b<192 = MFMA logits GEMM L = 0.5*Xb@Wb^T (bn=b%24, bm=b/24);
//         b>=192 = topT[k][s] = topics[s][k]*tninv[s]. ----------------------
__global__ __launch_bounds__(256) void gt_kernel(
    const unsigned short* __restrict__ Xb, const unsigned short* __restrict__ Wb,
    float* __restrict__ L, const float* __restrict__ topics,
    const float* __restrict__ tninv, float* __restrict__ topT) {
  __shared__ unsigned short As[128 * 32], Bs[128 * 32];
  int t = threadIdx.x;
  int b = blockIdx.x;
  if (b >= 192) {
    int idx = (b - 192) * 256 + t;  // = k*32 + s, < 32768
    int k = idx >> 5, s = idx & 31;
    topT[idx] = topics[(size_t)s * HH + k] * tninv[s];
    return;
  }
  int wave = t >> 6, ln = t & 63;
  int bn = b % 24, bm = b / 24;
  int wm = (wave >> 1) * 64, wn = (wave & 1) * 64;
  const unsigned short* ga = Xb + (size_t)(bm * 128 + (t >> 2)) * HH + (t & 3) * 8;
  const unsigned short* gb = Wb + (size_t)(bn * 128 + (t >> 2)) * HH + (t & 3) * 8;
  int lq = ln >> 4, lm = ln & 15;
  floatx4 acc[4][4];
#pragma unroll
  for (int i = 0; i < 4; ++i)
#pragma unroll
    for (int j = 0; j < 4; ++j) acc[i][j] = (floatx4)0.0f;

  for (int k0 = 0; k0 < HH; k0 += 32) {
    __syncthreads();
    gload16(ga + k0, As + t * 8);
    gload16(ga + (size_t)64 * HH + k0, As + 2048 + t * 8);
    gload16(gb + k0, Bs + t * 8);
    gload16(gb + (size_t)64 * HH + k0, Bs + 2048 + t * 8);
    __syncthreads();
    short8 af[4], bfr[4];
#pragma unroll
    for (int i = 0; i < 4; ++i)
      af[i] = *(const short8*)(As + (wm + i * 16 + lm) * 32 + lq * 8);
#pragma unroll
    for (int j = 0; j < 4; ++j)
      bfr[j] = *(const short8*)(Bs + (wn + j * 16 + lm) * 32 + lq * 8);
#pragma unroll
    for (int i = 0; i < 4; ++i)
#pragma unroll
      for (int j = 0; j < 4; ++j)
        acc[i][j] = __builtin_amdgcn_mfma_f32_16x16x32_bf16(af[i], bfr[j], acc[i][j], 0, 0, 0);
  }
  int row0 = bm * 128 + wm + lq * 4;
  int col0 = bn * 128 + wn + lm;
#pragma unroll
  for (int j = 0; j < 4; ++j) {
    int col = col0 + j * 16;
    if (col < NV) {
#pragma unroll
      for (int i = 0; i < 4; ++i) {
#pragma unroll
        for (int r = 0; r < 4; ++r)
          L[(size_t)(row0 + i * 16 + r) * NV + col] = acc[i][j][r] * 0.5f;
      }
    }
  }
}

// --- Kb[v][s]=bf16(exp(-20*M)) packed, KMt[v][s]=K*M fp32 ------------------
__global__ __launch_bounds__(256) void mk_kernel(
    const float* __restrict__ W_lm, const int* __restrict__ verbs,
    const float* __restrict__ topT, const float* __restrict__ vninv,
    unsigned* __restrict__ Kb, float* __restrict__ KMt) {
  __shared__ float red[4][64][33];
  int t = threadIdx.x, ln = t & 63, w = t >> 6;
  int v = blockIdx.x * 64 + ln;
  int vc = v < NV ? v : NV - 1;
  int kb = __builtin_amdgcn_readfirstlane(w) << 8;
  const float* wrow = W_lm + (size_t)verbs[vc] * HH + kb;
  const float* tb = topT + (size_t)kb * 32;
  float acc[32];
#pragma unroll
  for (int s = 0; s < 32; ++s) acc[s] = 0.0f;
  for (int kk = 0; kk < 256; kk += 4) {
    float4 w4 = *(const float4*)(wrow + kk);
    const float* tr = tb + kk * 32;
    const float* pw = (const float*)&w4;
#pragma unroll
    for (int d = 0; d < 4; ++d)
#pragma unroll
      for (int s = 0; s < 32; ++s) acc[s] = fmaf(pw[d], tr[d * 32 + s], acc[s]);
  }
#pragma unroll
  for (int s = 0; s < 32; ++s) red[w][ln][s] = acc[s];
  __syncthreads();
  for (int idx = t; idx < 1024; idx += 256) {
    int l = idx >> 4, pr = idx & 15;
    int vo = blockIdx.x * 64 + l;
    if (vo < NV) {
      int s0 = pr * 2, s1 = s0 + 1;
      float vi = vninv[vo];
      float d0 = red[0][l][s0] + red[1][l][s0] + red[2][l][s0] + red[3][l][s0];
      float d1 = red[0][l][s1] + red[1][l][s1] + red[2][l][s1] + red[3][l][s1];
      float M0 = 1.0f - d0 * vi, M1 = 1.0f - d1 * vi;
      float K0 = __expf(-20.0f * M0), K1 = __expf(-20.0f * M1);
      *(float2*)(KMt + (size_t)vo * 32 + s0) = make_float2(K0 * M0, K1 * M1);
      Kb[(size_t)vo * 16 + pr] = bf16r(K0) | (bf16r(K1) << 16);
    }
  }
}

// slot-split fused pass: pair (2k,2k+1) shares each v-row; lane parity p owns
// slots [16p,16p+16). Full w rebuilt via shfl_xor(.,1). 512 pairs x 6 rows.
template <bool STORE_T>
__device__ __forceinline__ void kpass_ss(
    const uint4* __restrict__ Kb, const float* __restrict__ bsh0,
    const float* __restrict__ bsh1, const float2* u0, const float2* u1,
    float2* z0, float2* z1, float* vsh0, float* vsh1, int pid, int p) {
#pragma unroll 3
  for (int i = 0; i < 6; ++i) {
    int v = pid + (i << 9);
    if (i < 5 || v < NV) {
      const uint4* kq = Kb + ((size_t)v << 2) + (p << 1);
      uint4 q0 = kq[0], q1 = kq[1];
      float2 kc[8];
      kc[0] = unpk2(q0.x); kc[1] = unpk2(q0.y);
      kc[2] = unpk2(q0.z); kc[3] = unpk2(q0.w);
      kc[4] = unpk2(q1.x); kc[5] = unpk2(q1.y);
      kc[6] = unpk2(q1.z); kc[7] = unpk2(q1.w);
      float2 w0 = make_float2(0.f, 0.f), w1 = make_float2(0.f, 0.f);
#pragma unroll
      for (int j = 0; j < 8; ++j) { pk_fma_acc(w0, kc[j], u0[j]); pk_fma_acc(w1, kc[j], u1[j]); }
      float s0 = w0.x + w0.y, s1 = w1.x + w1.y;
      s0 += __shfl_xor(s0, 1, 64);
      s1 += __shfl_xor(s1, 1, 64);
      float t0 = bsh0[v] * __builtin_amdgcn_rcpf(s0);
      float t1 = bsh1[v] * __builtin_amdgcn_rcpf(s1);
      if (STORE_T && !p) { vsh0[v] = t0; vsh1[v] = t1; }
      float2 t0p = make_float2(t0, t0), t1p = make_float2(t1, t1);
#pragma unroll
      for (int j = 0; j < 8; ++j) { pk_fma_acc(z0[j], kc[j], t0p); pk_fma_acc(z1[j], kc[j], t1p); }
    }
  }
}

__device__ __forceinline__ void errpass_ss(
    const uint4* __restrict__ Kb, const float* __restrict__ bsh0,
    const float* __restrict__ bsh1, const float2* u0, const float2* u1,
    const float* vsh0, const float* vsh1, float& ep0, float& ep1,
    int pid, int p) {
#pragma unroll 3
  for (int i = 0; i < 6; ++i) {
    int v = pid + (i << 9);
    if (i < 5 || v < NV) {
      const uint4* kq = Kb + ((size_t)v << 2) + (p << 1);
      uint4 q0 = kq[0], q1 = kq[1];
      float2 kc[8];
      kc[0] = unpk2(q0.x); kc[1] = unpk2(q0.y);
      kc[2] = unpk2(q0.z); kc[3] = unpk2(q0.w);
      kc[4] = unpk2(q1.x); kc[5] = unpk2(q1.y);
      kc[6] = unpk2(q1.z); kc[7] = unpk2(q1.w);
      float2 w0 = make_float2(0.f, 0.f), w1 = make_float2(0.f, 0.f);
#pragma unroll
      for (int j = 0; j < 8; ++j) { pk_fma_acc(w0, kc[j], u0[j]); pk_fma_acc(w1, kc[j], u1[j]); }
      float s0 = w0.x + w0.y, s1 = w1.x + w1.y;
      s0 += __shfl_xor(s0, 1, 64);
      s1 += __shfl_xor(s1, 1, 64);
      if (!p) {
        ep0 += fabsf(vsh0[v] * s0 - bsh0[v]);
        ep1 += fabsf(vsh1[v] * s1 - bsh1[v]);
      }
    }
  }
}

// 16-element reduce-scatter butterfly over strides 2..32.
__device__ __forceinline__ float waveRS16(float* z, int ln) {
  int cnt = 16;
#pragma unroll
  for (int d = 2; d <= 16; d <<= 1) {
    int half = cnt >> 1;
    bool hi = (ln & d) != 0;
#pragma unroll
    for (int k = 0; k < 8; ++k) {
      if (k < half) {
        float a = z[k], b = z[half + k];
        z[k] = hi ? b : a;
        z[half + k] = hi ? a : b;
      }
    }
#pragma unroll
    for (int k = 0; k < 8; ++k)
      if (k < half) z[k] += __shfl_xor(z[half + k], d, 64);
    cnt = half;
  }
  return z[0] + __shfl_xor(z[0], 32, 64);
}

// --- Sinkhorn: 256 blocks x 1024 threads; 2 columns per block, slot-split ---
// Prologue fuses softmax (bT rows) and a_kernel (aT rows) bitwise-exactly.
// Loop/epilogue = R15 (block-local convergence).
__global__ __launch_bounds__(1024) void sinkhorn_kernel(
    const uint4* __restrict__ Kb, const float* __restrict__ KMt,
    const float* __restrict__ L, const float* __restrict__ outputs,
    const float* __restrict__ W_lin, const float* __restrict__ b_lin,
    unsigned* __restrict__ slots, float* __restrict__ outp) {
  const int t = threadIdx.x;
  const int w = t >> 6, ln = t & 63;   // 16 waves
  const int p = t & 1, pid = t >> 1;   // 512 pairs
  const int col0 = blockIdx.x << 1;
  float* accres = (float*)(slots + 64);
  unsigned* done = slots + 65;

  __shared__ float zred[2][16][32];
  __shared__ float ush[2][32];
  __shared__ float sredA[16], sredB[16];
  __shared__ unsigned ebits;
  __shared__ float vsh0[3072], vsh1[3072];
  __shared__ float bsh0[3072], bsh1[3072];
  __shared__ float orow[2][512];
  __shared__ float lgs[2][33];
  __shared__ float ash[2][32];
  __shared__ float rdA[2][4], rdB[2][4], rdC[2][4];
  float* ushf = &ush[0][0];

  // slot this lane owns after waveRS16
  const int sl = ((ln & 1) << 4) | ((ln & 2) << 2) | (ln & 4) |
                 ((ln & 8) >> 2) | ((ln & 16) >> 4);

  // ---- fused prologue: softmax rows col0,col0+1 -> bsh; aT rows -> ash ----
  // softmax: waves 0-3 = row0 (threads tt=t in [0,256)), waves 8-11 = row1
  // (tt=t-512). Replicates old softmax_kernel order bitwise (exp values
  // stored in bsh/vsh scratch instead of recomputed — deterministic).
  // a: wave 4 = row0, wave 6 = row1; replicates old a_kernel serially.
  const int sg = (w < 4) ? 0 : ((w >= 8 && w < 12) ? 1 : -1);
  const int ag = (w == 4) ? 0 : ((w == 6) ? 1 : -1);
  // Phase A
  if (sg >= 0) {
    int tt = (sg == 0) ? t : (t - 512);
    const float* r1p = L + (size_t)(col0 + sg) * NV;
    const float* r2p = L + (size_t)(512 + col0 + sg) * NV;
    float* esh1 = sg ? bsh1 : bsh0;
    float* esh2 = sg ? vsh1 : vsh0;
    float s1 = 0.0f, s2 = 0.0f;
    for (int v = tt; v < NV; v += 256) {
      float e1 = __expf(r1p[v]), e2 = __expf(r2p[v]);
      esh1[v] = e1; esh2[v] = e2;
      s1 += e1; s2 += e2;
    }
    s1 = wave_sum(s1); s2 = wave_sum(s2);
    if (ln == 0) { rdA[sg][w & 3] = s1; rdB[sg][w & 3] = s2; }
  } else if (ag >= 0) {
    const float* osrc = outputs + (size_t)(col0 + ag) * 512;
    *(float4*)(&orow[ag][ln * 8])     = *(const float4*)(osrc + ln * 8);
    *(float4*)(&orow[ag][ln * 8 + 4]) = *(const float4*)(osrc + ln * 8 + 4);
    if (ln < 33) {
      float acc = b_lin[ln];
      for (int k = 0; k < 512; ++k)
        acc = fmaf(orow[ag][k], W_lin[(size_t)ln * 512 + k], acc);
      lgs[ag][ln] = acc;
    }
  }
  __syncthreads();
  // Phase B
  if (sg >= 0) {
    int tt = (sg == 0) ? t : (t - 512);
    float s1 = rdA[sg][0] + rdA[sg][1] + rdA[sg][2] + rdA[sg][3];
    float s2 = rdB[sg][0] + rdB[sg][1] + rdB[sg][2] + rdB[sg][3];
    float i1 = 0.5f / s1, i2 = 0.5f / s2;
    float* esh1 = sg ? bsh1 : bsh0;
    float* esh2 = sg ? vsh1 : vsh0;
    float rs = 0.0f;
    for (int v = tt; v < NV; v += 256) {
      float o = esh1[v] * i1 + esh2[v] * i2;
      esh1[v] = o; rs += o;
    }
    rs = wave_sum(rs);
    if (ln == 0) rdC[sg][w & 3] = rs;
  } else if (ag >= 0 && ln == 0) {
    float m = lgs[ag][1];
    for (int i = 2; i < 33; ++i) m = fmaxf(m, lgs[ag][i]);
    float ssum = 0.0f;
    for (int i = 1; i < 33; ++i) ssum += __expf(lgs[ag][i] - m);
    for (int i = 1; i < 33; ++i) ash[ag][i - 1] = __expf(lgs[ag][i] - m) / ssum;
  }
  __syncthreads();
  // Phase C
  if (sg >= 0) {
    int tt = (sg == 0) ? t : (t - 512);
    float rinv = 1.0f / (rdC[sg][0] + rdC[sg][1] + rdC[sg][2] + rdC[sg][3]);
    float* esh1 = sg ? bsh1 : bsh0;
    for (int v = tt; v < NV; v += 256) esh1[v] *= rinv;
  }
  float2 u0[8], u1[8];
#pragma unroll
  for (int j = 0; j < 8; ++j) {
    u0[j] = make_float2(1.0f / 32.0f, 1.0f / 32.0f);
    u1[j] = make_float2(1.0f / 32.0f, 1.0f / 32.0f);
  }
  if (t < 64) ushf[t] = 1.0f / 32.0f;
  __syncthreads();  // bsh + ash ready
  const float areg = (t < 64) ? ash[t >> 5][t & 31] : 0.0f;
  float err = 1.0f;
  int cpt = 0;

  while (cpt < 1000 && err > 0.005f) {
    float2 z0[8], z1[8];
#pragma unroll
    for (int j = 0; j < 8; ++j) { z0[j] = make_float2(0.0f, 0.0f); z1[j] = make_float2(0.0f, 0.0f); }
    kpass_ss<false>(Kb, bsh0, bsh1, u0, u1, z0, z1, vsh0, vsh1, pid, p);
    float r0 = waveRS16((float*)z0, ln), r1 = waveRS16((float*)z1, ln);
    __syncthreads();
    if (ln < 32) { zred[0][w][sl] = r0; zred[1][w][sl] = r1; }
    __syncthreads();
    if (t < 64) {
      int c = t >> 5, s = t & 31;
      float zz = 0.0f;
#pragma unroll
      for (int k = 0; k < 16; ++k) zz += zred[c][k][s];
      ushf[t] = areg * __builtin_amdgcn_rcpf(zz);
    }
    __syncthreads();
#pragma unroll
    for (int q = 0; q < 4; ++q) {
      *(float4*)((float*)u0 + q * 4) = *(float4*)(&ush[0][(p << 4) + q * 4]);
      *(float4*)((float*)u1 + q * 4) = *(float4*)(&ush[1][(p << 4) + q * 4]);
    }
    ++cpt;

    if (cpt % 20 == 1 || cpt == 1000) {
      // v = b/(K^T u) (store t into LDS); u = a/(K v)
#pragma unroll
      for (int j = 0; j < 8; ++j) { z0[j] = make_float2(0.0f, 0.0f); z1[j] = make_float2(0.0f, 0.0f); }
      kpass_ss<true>(Kb, bsh0, bsh1, u0, u1, z0, z1, vsh0, vsh1, pid, p);
      r0 = waveRS16((float*)z0, ln); r1 = waveRS16((float*)z1, ln);
      __syncthreads();
      if (ln < 32) { zred[0][w][sl] = r0; zred[1][w][sl] = r1; }
      __syncthreads();
      if (t < 64) {
        int c = t >> 5, s = t & 31;
        float zz = 0.0f;
#pragma unroll
        for (int k = 0; k < 16; ++k) zz += zred[c][k][s];
        ushf[t] = areg * __builtin_amdgcn_rcpf(zz);
      }
      __syncthreads();
#pragma unroll
      for (int q = 0; q < 4; ++q) {
        *(float4*)((float*)u0 + q * 4) = *(float4*)(&ush[0][(p << 4) + q * 4]);
        *(float4*)((float*)u1 + q * 4) = *(float4*)(&ush[1][(p << 4) + q * 4]);
      }
      float ep0 = 0.0f, ep1 = 0.0f;
      errpass_ss(Kb, bsh0, bsh1, u0, u1, vsh0, vsh1, ep0, ep1, pid, p);
      ep0 = wave_sum(ep0); ep1 = wave_sum(ep1);
      if (ln == 0) { sredA[w] = ep0; sredB[w] = ep1; }
      __syncthreads();
      if (t == 0) {
        float e0 = 0.0f, e1 = 0.0f;
#pragma unroll
        for (int k = 0; k < 16; ++k) { e0 += sredA[k]; e1 += sredB[k]; }
        ebits = __float_as_uint(fmaxf(e0, e1));  // block-local err
      }
      __syncthreads();
      err = __uint_as_float(ebits);
    }
  }

  // ---- epilogue: out_col = sum_s u[s] * sum_v KM[v][s]*t[v] ----
  float y0[16], y1[16];
#pragma unroll
  for (int s = 0; s < 16; ++s) { y0[s] = 0.0f; y1[s] = 0.0f; }
#pragma unroll 3
  for (int i = 0; i < 6; ++i) {
    int v = pid + (i << 9);
    if (i < 5 || v < NV) {
      const float4* kp = (const float4*)(KMt + (size_t)v * 32 + (p << 4));
      float kc[16];
#pragma unroll
      for (int q = 0; q < 4; ++q) *(float4*)(kc + q * 4) = kp[q];
      float x0 = vsh0[v], x1 = vsh1[v];
#pragma unroll
      for (int s = 0; s < 16; ++s) { y0[s] = fmaf(kc[s], x0, y0[s]); y1[s] = fmaf(kc[s], x1, y1[s]); }
    }
  }
  float r0 = waveRS16(y0, ln), r1 = waveRS16(y1, ln);
  __syncthreads();
  if (ln < 32) { zred[0][w][sl] = r0; zred[1][w][sl] = r1; }
  __syncthreads();
  if (t < 64) {
    int c = t >> 5, s = t & 31;
    float ys = 0.0f;
#pragma unroll
    for (int k = 0; k < 16; ++k) ys += zred[c][k][s];
    float pp = ys * ushf[t];
#pragma unroll
    for (int off = 1; off <= 16; off <<= 1) pp += __shfl_xor(pp, off, 64);
    float other = __shfl_xor(pp, 32, 64);
    if (t == 0) {
      atomicAdd(accres, pp + other);
      __hip_atomic_fetch_add(done, 1u, __ATOMIC_RELEASE, __HIP_MEMORY_SCOPE_AGENT);
    }
  }
  if (blockIdx.x == 0 && t == 0) {
    while (__hip_atomic_load(done, __ATOMIC_ACQUIRE, __HIP_MEMORY_SCOPE_AGENT) < 256u) {
      __builtin_amdgcn_s_sleep(1);
    }
    unsigned ab = __hip_atomic_load((unsigned*)accres, __ATOMIC_RELAXED, __HIP_MEMORY_SCOPE_AGENT);
    outp[0] = __uint_as_float(ab) / 512.0f;
  }
}

// ---------------------------------------------------------------------------
extern "C" void kernel_launch(void* const* d_in, const int* in_sizes, int n_in,
                              void* d_out, int out_size, void* d_ws, size_t ws_size,
                              hipStream_t stream) {
  (void)in_sizes; (void)n_in; (void)out_size; (void)ws_size;
  const float* inputs  = (const float*)d_in[0];
  const float* outputs = (const float*)d_in[1];
  const float* W_lm    = (const float*)d_in[2];
  const float* W_lin   = (const float*)d_in[3];
  const float* b_lin   = (const float*)d_in[4];
  const float* topics  = (const float*)d_in[5];
  const int*   verbs   = (const int*)d_in[6];
  float* out = (float*)d_out;

  char* ws = (char*)d_ws;
  float*    L     = (float*)(ws);                 // 12,288,000 B (1024x3000)
  unsigned* Kb    = (unsigned*)(ws + 12353536);   //    192,000 B (bf16 x2)
  float*    KMt   = (float*)(ws + 12545536);      //    384,000 B
  float*    topT  = (float*)(ws + 12929536);      //    131,072 B
  float*    vninv = (float*)(ws + 13060608);      //     12,032 B
  float*    tninv = (float*)(ws + 13072640);      //        128 B
  unsigned* slots = (unsigned*)(ws + 13072768);   //        512 B
  unsigned short* Xb = (unsigned short*)(ws + 13073280);  // 2,097,152 B
  unsigned short* Wb = (unsigned short*)(ws + 15170432);  // 6,291,456 B

  hipMemsetAsync((void*)slots, 0, 512, stream);

  prep_kernel<<<3616, 256, 0, stream>>>(W_lm, topics, verbs, vninv, tninv, Wb, inputs, Xb);
  gt_kernel<<<320, 256, 0, stream>>>(Xb, Wb, L, topics, tninv, topT);
  mk_kernel<<<47, 256, 0, stream>>>(W_lm, verbs, topT, vninv, Kb, KMt);
  sinkhorn_kernel<<<256, 1024, 0, stream>>>((const uint4*)Kb, KMt, L, outputs,
                                            W_lin, b_lin, slots, out);
}